// Round 11
// baseline (26.124 us; speedup 1.0000x reference)
//
#include <hip/hip_runtime.h>

#define SEQ 2048
#define NH 8
#define NB 4

typedef unsigned int u32;
typedef unsigned long long u64;
typedef short bf16x8_t __attribute__((ext_vector_type(8)));
typedef float f32x16_t __attribute__((ext_vector_type(16)));

// 2^x, raw v_exp_f32 (proven R1/R2/R7-R10)
__device__ __forceinline__ float exp2_fast(float x) {
    float r; asm("v_exp_f32 %0, %1" : "=v"(r) : "v"(x)); return r;
}
// pack 2 f32 -> 2 bf16, round-half-up: 2x v_add + 1x v_perm_b32 (proven R7-R10)
__device__ __forceinline__ u32 pkb(float a, float b) {
    const u32 ua = __builtin_bit_cast(u32, a) + 0x8000u;
    const u32 ub = __builtin_bit_cast(u32, b) + 0x8000u;
    return __builtin_amdgcn_perm(ub, ua, 0x07060302u);  // {ub.hi16, ua.hi16}
}
// {lo16 of a, lo16 of b<<16}
__device__ __forceinline__ u32 merge16(u32 lo, u32 hi) {
    return __builtin_amdgcn_perm(hi, lo, 0x05040100u);  // {hi.lo16, lo.lo16}
}

union UBv { bf16x8_t v; u32 u[4]; };

__global__ __launch_bounds__(256)
void attn_mfma(const float* __restrict__ x, const float* __restrict__ Wq,
               const float* __restrict__ Wk, const float* __restrict__ Wv,
               float* __restrict__ out) {
    // VT4: [kt=128][d=4][pos=16] bf16; rows d={x0,x1,x2,ones}; key m of a 16-tile
    //      stored at pos pi(m) (pi = bit2<->bit3 swap, self-inverse)   (16 KB)
    //      serves PV-B as 2x b128 AND scores-A via 3x u16 (pi-baked addrs)
    // RED: cross-wave partials                                          (2 KB)
    __shared__ __align__(16) char VT4[128 * 128];
    __shared__ __align__(16) float RED[4][8][16];

    const int tid = threadIdx.x;
    const int blk = blockIdx.x;
    const int qb  = blk & 63;      // 32-query tile (64 per bh)
    const int bh  = blk >> 6;
    const int h   = bh & 7;
    const int b   = bh >> 3;

    // ---- staging: 8 keys per thread, pi-permuted positions ----
    {
        const float4* xg = (const float4*)(x + b * SEQ * 3);
        float xv[24];
        const float4 t0 = xg[tid * 6 + 0]; xv[0]=t0.x; xv[1]=t0.y; xv[2]=t0.z; xv[3]=t0.w;
        const float4 t1 = xg[tid * 6 + 1]; xv[4]=t1.x; xv[5]=t1.y; xv[6]=t1.z; xv[7]=t1.w;
        const float4 t2 = xg[tid * 6 + 2]; xv[8]=t2.x; xv[9]=t2.y; xv[10]=t2.z; xv[11]=t2.w;
        const float4 t3 = xg[tid * 6 + 3]; xv[12]=t3.x; xv[13]=t3.y; xv[14]=t3.z; xv[15]=t3.w;
        const float4 t4 = xg[tid * 6 + 4]; xv[16]=t4.x; xv[17]=t4.y; xv[18]=t4.z; xv[19]=t4.w;
        const float4 t5 = xg[tid * 6 + 5]; xv[20]=t5.x; xv[21]=t5.y; xv[22]=t5.z; xv[23]=t5.w;
        const int kt   = tid >> 1;        // 16-key tile
        const int half = tid & 1;         // keys 0-7 or 8-15 of the tile
        const int slotA = half * 4;       // pi maps {h*8..h*8+3}->{h*4..}, {+4..+7}->{+8..}
        char* base = VT4 + kt * 128;
#pragma unroll
        for (int d = 0; d < 3; ++d) {
            uint2 wa, wb;
            wa.x = pkb(xv[0 + d],  xv[3 + d]);
            wa.y = pkb(xv[6 + d],  xv[9 + d]);
            wb.x = pkb(xv[12 + d], xv[15 + d]);
            wb.y = pkb(xv[18 + d], xv[21 + d]);
            *(uint2*)(base + d * 32 + slotA * 2)      = wa;   // pos slotA..slotA+3
            *(uint2*)(base + d * 32 + slotA * 2 + 16) = wb;   // pos slotA+8..+11
        }
        uint4 ones; ones.x = ones.y = ones.z = ones.w = 0x3F803F80u;
        *(uint4*)(base + 96 + half * 16) = ones;              // d=3 row (order irrelevant)
    }

    // per-head weights (wave-uniform h -> scalar loads)
    const float* wqp = Wq + h * 9;
    const float* wkp = Wk + h * 9;
    const float* wvp = Wv + h * 9;
    float wq_[9], wk_[9], wv_[9];
#pragma unroll
    for (int i = 0; i < 9; ++i) { wq_[i] = wqp[i]; wk_[i] = wkp[i]; wv_[i] = wvp[i]; }

    const int lane = tid & 63;
    const int wid  = tid >> 6;    // k-split: 512 keys per wave
    const int ql   = lane & 31;
    const int q    = qb * 32 + ql;

    // u = (x_q Wq) Wk^T * scale * log2(e) from f32 x (global, L2-hot)
    const float* gq = x + b * SEQ * 3 + q * 3;
    const float xq0 = gq[0], xq1 = gq[1], xq2 = gq[2];
    const float Q0 = xq0 * wq_[0] + xq1 * wq_[3] + xq2 * wq_[6];
    const float Q1 = xq0 * wq_[1] + xq1 * wq_[4] + xq2 * wq_[7];
    const float Q2 = xq0 * wq_[2] + xq1 * wq_[5] + xq2 * wq_[8];
    const float cc = 0.5773502691896258f * 1.4426950408889634f;
    const float u0 = (Q0 * wk_[0] + Q1 * wk_[1] + Q2 * wk_[2]) * cc;
    const float u1 = (Q0 * wk_[3] + Q1 * wk_[4] + Q2 * wk_[5]) * cc;
    const float u2 = (Q0 * wk_[6] + Q1 * wk_[7] + Q2 * wk_[8]) * cc;

    __syncthreads();

    // scores-mfma B operand: B[k, col=q]; lanes>=32 (k=8..15) zero
    UBv Bs;
    Bs.u[0] = (lane < 32) ? pkb(u0, u1) : 0u;
    Bs.u[1] = (lane < 32) ? pkb(u2, 0.f) : 0u;
    Bs.u[2] = 0u; Bs.u[3] = 0u;

    // per-wave addresses
    const int kbase = wid * 512;
    const int m     = ql;                         // A row = key-within-32-tile
    const int pim   = (m & 0x13) | ((m & 4) << 1) | ((m & 8) >> 1);  // pi(m&15) + (m&16)
    const char* xa  = VT4 + (kbase >> 4) * 128 + (m >> 4) * 128 + ((pim & 15) * 2);
    const char* vb  = VT4 + (kbase >> 4) * 128 + (lane & 3) * 32 + (lane >> 5) * 16;

    f32x16_t pvC = {};  // C[row=q', col: 0..3 = {a0,a1,a2,l} (cols repeat mod 4)]
    f32x16_t zc  = {};

    // ---- software-pipelined main loop: 16 k-tiles of 32 keys per wave ----
    // prologue: tile 0 A-frag + scores-MFMA
    UBv Af;
    Af.u[0] = merge16((u32)*(const unsigned short*)(xa + 0),
                      (u32)*(const unsigned short*)(xa + 32));
    Af.u[1] = (u32)*(const unsigned short*)(xa + 64);
    Af.u[2] = 0u; Af.u[3] = 0u;
    f32x16_t sc = __builtin_amdgcn_mfma_f32_32x32x16_bf16(Af.v, Bs.v, zc, 0, 0, 0);

#pragma unroll
    for (int t = 0; t < 16; ++t) {
        // B-frag b128 loads for tile t (consumed by PV ~150 cyc later)
        const uint4 bv0 = *(const uint4*)(vb + t * 256);
        const uint4 bv1 = *(const uint4*)(vb + t * 256 + 128);
        // A prefetch for tile t+1
        u32 nA0 = 0u, nA1 = 0u;
        if (t < 15) {
            nA0 = merge16((u32)*(const unsigned short*)(xa + (t + 1) * 256 + 0),
                          (u32)*(const unsigned short*)(xa + (t + 1) * 256 + 32));
            nA1 = (u32)*(const unsigned short*)(xa + (t + 1) * 256 + 64);
        }

        // exp + pack of tile t scores (covers load latency)
        UBv PA;
        PA.u[0] = pkb(exp2_fast(sc[0]), exp2_fast(sc[1]));
        PA.u[1] = pkb(exp2_fast(sc[2]), exp2_fast(sc[3]));
        PA.u[2] = pkb(exp2_fast(sc[4]), exp2_fast(sc[5]));
        PA.u[3] = pkb(exp2_fast(sc[6]), exp2_fast(sc[7]));
        UBv PB;
        PB.u[0] = pkb(exp2_fast(sc[8]),  exp2_fast(sc[9]));
        PB.u[1] = pkb(exp2_fast(sc[10]), exp2_fast(sc[11]));
        PB.u[2] = pkb(exp2_fast(sc[12]), exp2_fast(sc[13]));
        PB.u[3] = pkb(exp2_fast(sc[14]), exp2_fast(sc[15]));

        // PV MFMAs for tile t
        UBv B0; B0.u[0] = bv0.x; B0.u[1] = bv0.y; B0.u[2] = bv0.z; B0.u[3] = bv0.w;
        pvC = __builtin_amdgcn_mfma_f32_32x32x16_bf16(PA.v, B0.v, pvC, 0, 0, 0);
        UBv B1; B1.u[0] = bv1.x; B1.u[1] = bv1.y; B1.u[2] = bv1.z; B1.u[3] = bv1.w;
        pvC = __builtin_amdgcn_mfma_f32_32x32x16_bf16(PB.v, B1.v, pvC, 0, 0, 0);

        // scores-MFMA for tile t+1
        if (t < 15) {
            Af.u[0] = nA0; Af.u[1] = nA1;
            sc = __builtin_amdgcn_mfma_f32_32x32x16_bf16(Af.v, Bs.v, zc, 0, 0, 0);
        }
    }

    // ---- merge 4 k-splits + epilogue ----
    const int d31 = lane & 31;
    if (d31 < 4) {
        const int slot = ((lane >> 5) << 2) | d31;
#pragma unroll
        for (int i = 0; i < 4; ++i) {
            float4 w; w.x = pvC[i * 4 + 0]; w.y = pvC[i * 4 + 1];
            w.z = pvC[i * 4 + 2]; w.w = pvC[i * 4 + 3];
            *(float4*)&RED[wid][slot][i * 4] = w;
        }
    }
    __syncthreads();

    if (wid == 0 && lane < 32) {
        const int qrow = lane;
        const int hh2 = (qrow >> 2) & 1;
        const int r   = (qrow & 3) | ((qrow >> 3) << 2);
        float acc[4];
#pragma unroll
        for (int d = 0; d < 4; ++d)
            acc[d] = (RED[0][hh2 * 4 + d][r] + RED[1][hh2 * 4 + d][r])
                   + (RED[2][hh2 * 4 + d][r] + RED[3][hh2 * 4 + d][r]);
        const float inv = 1.0f / fmaxf(acc[3], 1e-37f);
        const float r0 = acc[0] * inv, r1 = acc[1] * inv, r2 = acc[2] * inv;
        const float o0 = r0 * wv_[0] + r1 * wv_[3] + r2 * wv_[6];
        const float o1 = r0 * wv_[1] + r1 * wv_[4] + r2 * wv_[7];
        const float o2 = r0 * wv_[2] + r1 * wv_[5] + r2 * wv_[8];
        const int qg = qb * 32 + qrow;
        const int o  = bh * (SEQ * 3) + qg * 3;
        const int second = NB * NH * SEQ * 3;
        out[o + 0] = o0; out[o + 1] = o1; out[o + 2] = o2;
        out[o + second + 0] = o0; out[o + second + 1] = o1; out[o + second + 2] = o2;
    }
}

extern "C" void kernel_launch(void* const* d_in, const int* in_sizes, int n_in,
                              void* d_out, int out_size, void* d_ws, size_t ws_size,
                              hipStream_t stream) {
    const float* x  = (const float*)d_in[0];
    const float* Wq = (const float*)d_in[1];
    const float* Wk = (const float*)d_in[2];
    const float* Wv = (const float*)d_in[3];
    float* out = (float*)d_out;
    (void)in_sizes; (void)n_in; (void)d_ws; (void)ws_size; (void)out_size;

    const int grid = NB * NH * (SEQ / 32);  // 2048 blocks = 8/CU resident
    attn_mfma<<<grid, 256, 0, stream>>>(x, Wq, Wk, Wv, out);
}

// Round 12
// 24.560 us; speedup vs baseline: 1.0637x; 1.0637x over previous
//
#include <hip/hip_runtime.h>

#define SEQ 2048
#define NH 8
#define NB 4

typedef unsigned int u32;
typedef short bf16x8_t __attribute__((ext_vector_type(8)));
typedef float f32x16_t __attribute__((ext_vector_type(16)));

// 2^x, raw v_exp_f32 (proven R1/R2/R7-R11)
__device__ __forceinline__ float exp2_fast(float x) {
    float r; asm("v_exp_f32 %0, %1" : "=v"(r) : "v"(x)); return r;
}
// pack 2 f32 -> 2 bf16, round-half-up (staging: accuracy matters, amortized)
__device__ __forceinline__ u32 pkb(float a, float b) {
    const u32 ua = __builtin_bit_cast(u32, a) + 0x8000u;
    const u32 ub = __builtin_bit_cast(u32, b) + 0x8000u;
    return __builtin_amdgcn_perm(ub, ua, 0x07060302u);  // {a.bf16, b.bf16}
}
// pack 2 f32 -> 2 bf16, TRUNCATE (P only: softmax renorm cancels bias) - 1 op
__device__ __forceinline__ u32 pkt(float a, float b) {
    return __builtin_amdgcn_perm(__builtin_bit_cast(u32, b),
                                 __builtin_bit_cast(u32, a), 0x07060302u);
}
// {lo16 of lo, lo16 of hi << 16}
__device__ __forceinline__ u32 merge16(u32 lo, u32 hi) {
    return __builtin_amdgcn_perm(hi, lo, 0x05040100u);
}

union UBv { bf16x8_t v; u32 u[4]; };

__global__ __launch_bounds__(256)
void attn_mfma(const float* __restrict__ x, const float* __restrict__ Wq,
               const float* __restrict__ Wk, const float* __restrict__ Wv,
               float* __restrict__ out) {
    // VT4: [kt=128][d=4][pos=16] bf16; rows d={x0,x1,x2,ones}; key m at pos pi(m)
    //      (pi = bit2<->bit3 swap). Serves PV-B (2x b128) + scores-A (3x u16). 16 KB
    // RED: [head][wid][slot][16] cross-wave partials                            4 KB
    __shared__ __align__(16) char VT4[128 * 128];
    __shared__ __align__(16) float RED[2][4][8][16];

    const int tid = threadIdx.x;
    const int blk = blockIdx.x;
    const int qb   = blk & 63;     // 32-query tile
    const int rest = blk >> 6;
    const int hp   = rest & 3;     // head pair
    const int b    = rest >> 2;
    const int h0   = hp * 2, h1 = h0 + 1;

    // ---- staging: 8 keys per thread, pi-permuted positions (proven R11) ----
    {
        const float4* xg = (const float4*)(x + b * SEQ * 3);
        float xv[24];
        const float4 t0 = xg[tid * 6 + 0]; xv[0]=t0.x; xv[1]=t0.y; xv[2]=t0.z; xv[3]=t0.w;
        const float4 t1 = xg[tid * 6 + 1]; xv[4]=t1.x; xv[5]=t1.y; xv[6]=t1.z; xv[7]=t1.w;
        const float4 t2 = xg[tid * 6 + 2]; xv[8]=t2.x; xv[9]=t2.y; xv[10]=t2.z; xv[11]=t2.w;
        const float4 t3 = xg[tid * 6 + 3]; xv[12]=t3.x; xv[13]=t3.y; xv[14]=t3.z; xv[15]=t3.w;
        const float4 t4 = xg[tid * 6 + 4]; xv[16]=t4.x; xv[17]=t4.y; xv[18]=t4.z; xv[19]=t4.w;
        const float4 t5 = xg[tid * 6 + 5]; xv[20]=t5.x; xv[21]=t5.y; xv[22]=t5.z; xv[23]=t5.w;
        const int kt   = tid >> 1;
        const int half = tid & 1;
        const int slotA = half * 4;
        char* base = VT4 + kt * 128;
#pragma unroll
        for (int d = 0; d < 3; ++d) {
            uint2 wa, wb;
            wa.x = pkb(xv[0 + d],  xv[3 + d]);
            wa.y = pkb(xv[6 + d],  xv[9 + d]);
            wb.x = pkb(xv[12 + d], xv[15 + d]);
            wb.y = pkb(xv[18 + d], xv[21 + d]);
            *(uint2*)(base + d * 32 + slotA * 2)      = wa;
            *(uint2*)(base + d * 32 + slotA * 2 + 16) = wb;
        }
        uint4 ones; ones.x = ones.y = ones.z = ones.w = 0x3F803F80u;
        *(uint4*)(base + 96 + half * 16) = ones;
    }

    const int lane = tid & 63;
    const int wid  = tid >> 6;    // k-split: 512 keys per wave
    const int ql   = lane & 31;
    const int q    = qb * 32 + ql;

    // u-vectors for BOTH heads (weights via wave-uniform scalar loads)
    const float* gq = x + b * SEQ * 3 + q * 3;
    const float xq0 = gq[0], xq1 = gq[1], xq2 = gq[2];
    const float cc = 0.5773502691896258f * 1.4426950408889634f;
    float u00, u01, u02, u10, u11, u12;
    {
        const float* wqp = Wq + h0 * 9; const float* wkp = Wk + h0 * 9;
        const float Q0 = xq0 * wqp[0] + xq1 * wqp[3] + xq2 * wqp[6];
        const float Q1 = xq0 * wqp[1] + xq1 * wqp[4] + xq2 * wqp[7];
        const float Q2 = xq0 * wqp[2] + xq1 * wqp[5] + xq2 * wqp[8];
        u00 = (Q0 * wkp[0] + Q1 * wkp[1] + Q2 * wkp[2]) * cc;
        u01 = (Q0 * wkp[3] + Q1 * wkp[4] + Q2 * wkp[5]) * cc;
        u02 = (Q0 * wkp[6] + Q1 * wkp[7] + Q2 * wkp[8]) * cc;
    }
    {
        const float* wqp = Wq + h1 * 9; const float* wkp = Wk + h1 * 9;
        const float Q0 = xq0 * wqp[0] + xq1 * wqp[3] + xq2 * wqp[6];
        const float Q1 = xq0 * wqp[1] + xq1 * wqp[4] + xq2 * wqp[7];
        const float Q2 = xq0 * wqp[2] + xq1 * wqp[5] + xq2 * wqp[8];
        u10 = (Q0 * wkp[0] + Q1 * wkp[1] + Q2 * wkp[2]) * cc;
        u11 = (Q0 * wkp[3] + Q1 * wkp[4] + Q2 * wkp[5]) * cc;
        u12 = (Q0 * wkp[6] + Q1 * wkp[7] + Q2 * wkp[8]) * cc;
    }

    __syncthreads();

    // scores-mfma B operands (k rows >= 4 zero; lanes>=32 all zero)
    UBv Bs0, Bs1;
    Bs0.u[0] = (lane < 32) ? pkb(u00, u01) : 0u;
    Bs0.u[1] = (lane < 32) ? pkb(u02, 0.f) : 0u;
    Bs0.u[2] = 0u; Bs0.u[3] = 0u;
    Bs1.u[0] = (lane < 32) ? pkb(u10, u11) : 0u;
    Bs1.u[1] = (lane < 32) ? pkb(u12, 0.f) : 0u;
    Bs1.u[2] = 0u; Bs1.u[3] = 0u;

    // per-wave addresses (proven R11)
    const int m   = ql;
    const int pim = (m & 0x13) | ((m & 4) << 1) | ((m & 8) >> 1);
    const char* xa = VT4 + wid * 4096 + (m >> 4) * 128 + ((pim & 15) * 2);
    const char* vb = VT4 + wid * 4096 + (lane & 3) * 32 + (lane >> 5) * 16;

    f32x16_t pvC0 = {};
    f32x16_t pvC1 = {};
    f32x16_t zc   = {};

    // ---- main loop: 16 k-tiles of 32 keys, 2 heads each ----
#pragma unroll
    for (int t = 0; t < 16; ++t) {
        // A frag (shared by both heads)
        UBv A;
        A.u[0] = merge16((u32)*(const unsigned short*)(xa + t * 256 + 0),
                         (u32)*(const unsigned short*)(xa + t * 256 + 32));
        A.u[1] = (u32)*(const unsigned short*)(xa + t * 256 + 64);
        A.u[2] = 0u; A.u[3] = 0u;
        // V frags (shared by both heads)
        const uint4 bv0 = *(const uint4*)(vb + t * 256);
        const uint4 bv1 = *(const uint4*)(vb + t * 256 + 128);
        UBv B0; B0.u[0] = bv0.x; B0.u[1] = bv0.y; B0.u[2] = bv0.z; B0.u[3] = bv0.w;
        UBv B1; B1.u[0] = bv1.x; B1.u[1] = bv1.y; B1.u[2] = bv1.z; B1.u[3] = bv1.w;

        const f32x16_t sc0 = __builtin_amdgcn_mfma_f32_32x32x16_bf16(A.v, Bs0.v, zc, 0, 0, 0);
        const f32x16_t sc1 = __builtin_amdgcn_mfma_f32_32x32x16_bf16(A.v, Bs1.v, zc, 0, 0, 0);

        // head0
        {
            UBv PA;
            PA.u[0] = pkt(exp2_fast(sc0[0]), exp2_fast(sc0[1]));
            PA.u[1] = pkt(exp2_fast(sc0[2]), exp2_fast(sc0[3]));
            PA.u[2] = pkt(exp2_fast(sc0[4]), exp2_fast(sc0[5]));
            PA.u[3] = pkt(exp2_fast(sc0[6]), exp2_fast(sc0[7]));
            pvC0 = __builtin_amdgcn_mfma_f32_32x32x16_bf16(PA.v, B0.v, pvC0, 0, 0, 0);
            UBv PB;
            PB.u[0] = pkt(exp2_fast(sc0[8]),  exp2_fast(sc0[9]));
            PB.u[1] = pkt(exp2_fast(sc0[10]), exp2_fast(sc0[11]));
            PB.u[2] = pkt(exp2_fast(sc0[12]), exp2_fast(sc0[13]));
            PB.u[3] = pkt(exp2_fast(sc0[14]), exp2_fast(sc0[15]));
            pvC0 = __builtin_amdgcn_mfma_f32_32x32x16_bf16(PB.v, B1.v, pvC0, 0, 0, 0);
        }
        // head1
        {
            UBv PA;
            PA.u[0] = pkt(exp2_fast(sc1[0]), exp2_fast(sc1[1]));
            PA.u[1] = pkt(exp2_fast(sc1[2]), exp2_fast(sc1[3]));
            PA.u[2] = pkt(exp2_fast(sc1[4]), exp2_fast(sc1[5]));
            PA.u[3] = pkt(exp2_fast(sc1[6]), exp2_fast(sc1[7]));
            pvC1 = __builtin_amdgcn_mfma_f32_32x32x16_bf16(PA.v, B0.v, pvC1, 0, 0, 0);
            UBv PB;
            PB.u[0] = pkt(exp2_fast(sc1[8]),  exp2_fast(sc1[9]));
            PB.u[1] = pkt(exp2_fast(sc1[10]), exp2_fast(sc1[11]));
            PB.u[2] = pkt(exp2_fast(sc1[12]), exp2_fast(sc1[13]));
            PB.u[3] = pkt(exp2_fast(sc1[14]), exp2_fast(sc1[15]));
            pvC1 = __builtin_amdgcn_mfma_f32_32x32x16_bf16(PB.v, B1.v, pvC1, 0, 0, 0);
        }
    }

    // ---- merge 4 k-splits + epilogue (both heads) ----
    const int d31 = lane & 31;
    if (d31 < 4) {
        const int slot = ((lane >> 5) << 2) | d31;
#pragma unroll
        for (int i = 0; i < 4; ++i) {
            float4 w0; w0.x = pvC0[i*4+0]; w0.y = pvC0[i*4+1]; w0.z = pvC0[i*4+2]; w0.w = pvC0[i*4+3];
            *(float4*)&RED[0][wid][slot][i * 4] = w0;
            float4 w1; w1.x = pvC1[i*4+0]; w1.y = pvC1[i*4+1]; w1.z = pvC1[i*4+2]; w1.w = pvC1[i*4+3];
            *(float4*)&RED[1][wid][slot][i * 4] = w1;
        }
    }
    __syncthreads();

    if (wid < 2 && lane < 32) {
        const int head = wid;
        const int hh   = head ? h1 : h0;
        const float* wvp = Wv + hh * 9;   // wave-uniform scalar loads
        const int qrow = lane;
        const int hh2 = (qrow >> 2) & 1;
        const int r   = (qrow & 3) | ((qrow >> 3) << 2);
        float acc[4];
#pragma unroll
        for (int d = 0; d < 4; ++d)
            acc[d] = (RED[head][0][hh2 * 4 + d][r] + RED[head][1][hh2 * 4 + d][r])
                   + (RED[head][2][hh2 * 4 + d][r] + RED[head][3][hh2 * 4 + d][r]);
        const float inv = 1.0f / fmaxf(acc[3], 1e-37f);
        const float r0 = acc[0] * inv, r1 = acc[1] * inv, r2 = acc[2] * inv;
        const float o0 = r0 * wvp[0] + r1 * wvp[3] + r2 * wvp[6];
        const float o1 = r0 * wvp[1] + r1 * wvp[4] + r2 * wvp[7];
        const float o2 = r0 * wvp[2] + r1 * wvp[5] + r2 * wvp[8];
        const int bhO = b * NH + hh;
        const int o   = bhO * (SEQ * 3) + (qb * 32 + qrow) * 3;
        const int second = NB * NH * SEQ * 3;
        out[o + 0] = o0; out[o + 1] = o1; out[o + 2] = o2;
        out[o + second + 0] = o0; out[o + second + 1] = o1; out[o + second + 2] = o2;
    }
}

extern "C" void kernel_launch(void* const* d_in, const int* in_sizes, int n_in,
                              void* d_out, int out_size, void* d_ws, size_t ws_size,
                              hipStream_t stream) {
    const float* x  = (const float*)d_in[0];
    const float* Wq = (const float*)d_in[1];
    const float* Wk = (const float*)d_in[2];
    const float* Wv = (const float*)d_in[3];
    float* out = (float*)d_out;
    (void)in_sizes; (void)n_in; (void)d_ws; (void)ws_size; (void)out_size;

    const int grid = NB * (NH / 2) * (SEQ / 32);  // 1024 blocks, 2 heads each
    attn_mfma<<<grid, 256, 0, stream>>>(x, Wq, Wk, Wv, out);
}

// Round 13
// 23.824 us; speedup vs baseline: 1.0965x; 1.0309x over previous
//
#include <hip/hip_runtime.h>

#define SEQ 2048
#define NH 8
#define NB 4

typedef unsigned int u32;
typedef short bf16x8_t __attribute__((ext_vector_type(8)));
typedef float f32x16_t __attribute__((ext_vector_type(16)));

// 2^x, raw v_exp_f32 (proven R1/R2/R7-R12)
__device__ __forceinline__ float exp2_fast(float x) {
    float r; asm("v_exp_f32 %0, %1" : "=v"(r) : "v"(x)); return r;
}
// pack 2 f32 -> 2 bf16, round-half-up (proven R7-R12)
__device__ __forceinline__ u32 pkb(float a, float b) {
    const u32 ua = __builtin_bit_cast(u32, a) + 0x8000u;
    const u32 ub = __builtin_bit_cast(u32, b) + 0x8000u;
    return __builtin_amdgcn_perm(ub, ua, 0x07060302u);  // {a.bf16, b.bf16}
}
// pack 2 f32 -> 2 bf16, TRUNCATE (P only: softmax renorm cancels bias)
__device__ __forceinline__ u32 pkt(float a, float b) {
    return __builtin_amdgcn_perm(__builtin_bit_cast(u32, b),
                                 __builtin_bit_cast(u32, a), 0x07060302u);
}

union UBv { bf16x8_t v; u32 u[4]; };

__global__ __launch_bounds__(256)
void attn_mfma(const float* __restrict__ x, const float* __restrict__ Wq,
               const float* __restrict__ Wk, const float* __restrict__ Wv,
               float* __restrict__ out) {
    // VT4: [kt=128][d=4][pos=16] bf16; rows d={x0,x1,x2,ones}; key m at pos pi(m)
    //      (pi = bit2<->bit3 swap). Serves PV-B (2x b128 broadcast reads). 16 KB
    // RED: [head][wid][slot][16] cross-wave partials                        4 KB
    __shared__ __align__(16) char VT4[128 * 128];
    __shared__ __align__(16) float RED[2][4][8][16];

    const int tid = threadIdx.x;
    const int blk = blockIdx.x;
    const int qb   = blk & 63;     // 32-query tile
    const int rest = blk >> 6;
    const int hp   = rest & 3;     // head pair
    const int b    = rest >> 2;
    const int h0   = hp * 2, h1 = h0 + 1;

    const float* xb = x + b * SEQ * 3;

    const int lane = tid & 63;
    const int wid  = tid >> 6;    // k-split: 512 keys per wave
    const int ql   = lane & 31;
    const int q    = qb * 32 + ql;
    const int kbase = wid * 512;

    // ---- A-fragments -> registers: lane's own key (kbase + t*32 + ql), 16 tiles.
    // Issue global loads first; latency hides under VT4 staging below. L2-hot.
    float ax0[16], ax1[16], ax2[16];
#pragma unroll
    for (int t = 0; t < 16; ++t) {
        const float* kp = xb + (kbase + t * 32 + ql) * 3;
        ax0[t] = kp[0]; ax1[t] = kp[1]; ax2[t] = kp[2];
    }

    // ---- staging: 8 keys per thread into VT4, pi-permuted positions (proven R11/R12)
    {
        const float4* xg = (const float4*)xb;
        float xv[24];
        const float4 t0 = xg[tid * 6 + 0]; xv[0]=t0.x; xv[1]=t0.y; xv[2]=t0.z; xv[3]=t0.w;
        const float4 t1 = xg[tid * 6 + 1]; xv[4]=t1.x; xv[5]=t1.y; xv[6]=t1.z; xv[7]=t1.w;
        const float4 t2 = xg[tid * 6 + 2]; xv[8]=t2.x; xv[9]=t2.y; xv[10]=t2.z; xv[11]=t2.w;
        const float4 t3 = xg[tid * 6 + 3]; xv[12]=t3.x; xv[13]=t3.y; xv[14]=t3.z; xv[15]=t3.w;
        const float4 t4 = xg[tid * 6 + 4]; xv[16]=t4.x; xv[17]=t4.y; xv[18]=t4.z; xv[19]=t4.w;
        const float4 t5 = xg[tid * 6 + 5]; xv[20]=t5.x; xv[21]=t5.y; xv[22]=t5.z; xv[23]=t5.w;
        const int kt   = tid >> 1;
        const int half = tid & 1;
        const int slotA = half * 4;
        char* base = VT4 + kt * 128;
#pragma unroll
        for (int d = 0; d < 3; ++d) {
            uint2 wa, wb;
            wa.x = pkb(xv[0 + d],  xv[3 + d]);
            wa.y = pkb(xv[6 + d],  xv[9 + d]);
            wb.x = pkb(xv[12 + d], xv[15 + d]);
            wb.y = pkb(xv[18 + d], xv[21 + d]);
            *(uint2*)(base + d * 32 + slotA * 2)      = wa;
            *(uint2*)(base + d * 32 + slotA * 2 + 16) = wb;
        }
        uint4 ones; ones.x = ones.y = ones.z = ones.w = 0x3F803F80u;
        *(uint4*)(base + 96 + half * 16) = ones;
    }

    // pack A-frag registers (identical bits to the R12 LDS path)
    u32 A0[16], A1[16];
#pragma unroll
    for (int t = 0; t < 16; ++t) {
        A0[t] = pkb(ax0[t], ax1[t]);
        A1[t] = pkb(ax2[t], 0.f);
    }

    // u-vectors for BOTH heads (wave-uniform weight scalar loads)
    const float* gq = xb + q * 3;
    const float xq0 = gq[0], xq1 = gq[1], xq2 = gq[2];
    const float cc = 0.5773502691896258f * 1.4426950408889634f;
    float u00, u01, u02, u10, u11, u12;
    {
        const float* wqp = Wq + h0 * 9; const float* wkp = Wk + h0 * 9;
        const float Q0 = xq0 * wqp[0] + xq1 * wqp[3] + xq2 * wqp[6];
        const float Q1 = xq0 * wqp[1] + xq1 * wqp[4] + xq2 * wqp[7];
        const float Q2 = xq0 * wqp[2] + xq1 * wqp[5] + xq2 * wqp[8];
        u00 = (Q0 * wkp[0] + Q1 * wkp[1] + Q2 * wkp[2]) * cc;
        u01 = (Q0 * wkp[3] + Q1 * wkp[4] + Q2 * wkp[5]) * cc;
        u02 = (Q0 * wkp[6] + Q1 * wkp[7] + Q2 * wkp[8]) * cc;
    }
    {
        const float* wqp = Wq + h1 * 9; const float* wkp = Wk + h1 * 9;
        const float Q0 = xq0 * wqp[0] + xq1 * wqp[3] + xq2 * wqp[6];
        const float Q1 = xq0 * wqp[1] + xq1 * wqp[4] + xq2 * wqp[7];
        const float Q2 = xq0 * wqp[2] + xq1 * wqp[5] + xq2 * wqp[8];
        u10 = (Q0 * wkp[0] + Q1 * wkp[1] + Q2 * wkp[2]) * cc;
        u11 = (Q0 * wkp[3] + Q1 * wkp[4] + Q2 * wkp[5]) * cc;
        u12 = (Q0 * wkp[6] + Q1 * wkp[7] + Q2 * wkp[8]) * cc;
    }

    __syncthreads();

    // scores-mfma B operands (k rows >= 4 zero; lanes>=32 all zero)
    UBv Bs0, Bs1;
    Bs0.u[0] = (lane < 32) ? pkb(u00, u01) : 0u;
    Bs0.u[1] = (lane < 32) ? pkb(u02, 0.f) : 0u;
    Bs0.u[2] = 0u; Bs0.u[3] = 0u;
    Bs1.u[0] = (lane < 32) ? pkb(u10, u11) : 0u;
    Bs1.u[1] = (lane < 32) ? pkb(u12, 0.f) : 0u;
    Bs1.u[2] = 0u; Bs1.u[3] = 0u;

    // PV-B address (proven R11/R12)
    const char* vb = VT4 + wid * 4096 + (lane & 3) * 32 + (lane >> 5) * 16;

    f32x16_t pvC0 = {};
    f32x16_t pvC1 = {};
    f32x16_t zc   = {};

    // ---- main loop: 16 k-tiles of 32 keys, 2 heads; only 2 ds ops per tile ----
#pragma unroll
    for (int t = 0; t < 16; ++t) {
        // V frags (broadcast b128; consumed by PV ~300 cy later)
        const uint4 bv0 = *(const uint4*)(vb + t * 256);
        const uint4 bv1 = *(const uint4*)(vb + t * 256 + 128);
        UBv B0; B0.u[0] = bv0.x; B0.u[1] = bv0.y; B0.u[2] = bv0.z; B0.u[3] = bv0.w;
        UBv B1; B1.u[0] = bv1.x; B1.u[1] = bv1.y; B1.u[2] = bv1.z; B1.u[3] = bv1.w;

        // A frag from registers: zero-latency operand
        UBv A; A.u[0] = A0[t]; A.u[1] = A1[t]; A.u[2] = 0u; A.u[3] = 0u;
        const f32x16_t sc0 = __builtin_amdgcn_mfma_f32_32x32x16_bf16(A.v, Bs0.v, zc, 0, 0, 0);
        const f32x16_t sc1 = __builtin_amdgcn_mfma_f32_32x32x16_bf16(A.v, Bs1.v, zc, 0, 0, 0);

        // head0
        {
            UBv PA;
            PA.u[0] = pkt(exp2_fast(sc0[0]), exp2_fast(sc0[1]));
            PA.u[1] = pkt(exp2_fast(sc0[2]), exp2_fast(sc0[3]));
            PA.u[2] = pkt(exp2_fast(sc0[4]), exp2_fast(sc0[5]));
            PA.u[3] = pkt(exp2_fast(sc0[6]), exp2_fast(sc0[7]));
            pvC0 = __builtin_amdgcn_mfma_f32_32x32x16_bf16(PA.v, B0.v, pvC0, 0, 0, 0);
            UBv PB;
            PB.u[0] = pkt(exp2_fast(sc0[8]),  exp2_fast(sc0[9]));
            PB.u[1] = pkt(exp2_fast(sc0[10]), exp2_fast(sc0[11]));
            PB.u[2] = pkt(exp2_fast(sc0[12]), exp2_fast(sc0[13]));
            PB.u[3] = pkt(exp2_fast(sc0[14]), exp2_fast(sc0[15]));
            pvC0 = __builtin_amdgcn_mfma_f32_32x32x16_bf16(PB.v, B1.v, pvC0, 0, 0, 0);
        }
        // head1
        {
            UBv PA;
            PA.u[0] = pkt(exp2_fast(sc1[0]), exp2_fast(sc1[1]));
            PA.u[1] = pkt(exp2_fast(sc1[2]), exp2_fast(sc1[3]));
            PA.u[2] = pkt(exp2_fast(sc1[4]), exp2_fast(sc1[5]));
            PA.u[3] = pkt(exp2_fast(sc1[6]), exp2_fast(sc1[7]));
            pvC1 = __builtin_amdgcn_mfma_f32_32x32x16_bf16(PA.v, B0.v, pvC1, 0, 0, 0);
            UBv PB;
            PB.u[0] = pkt(exp2_fast(sc1[8]),  exp2_fast(sc1[9]));
            PB.u[1] = pkt(exp2_fast(sc1[10]), exp2_fast(sc1[11]));
            PB.u[2] = pkt(exp2_fast(sc1[12]), exp2_fast(sc1[13]));
            PB.u[3] = pkt(exp2_fast(sc1[14]), exp2_fast(sc1[15]));
            pvC1 = __builtin_amdgcn_mfma_f32_32x32x16_bf16(PB.v, B1.v, pvC1, 0, 0, 0);
        }
    }

    // ---- merge 4 k-splits + epilogue (both heads) ----
    const int d31 = lane & 31;
    if (d31 < 4) {
        const int slot = ((lane >> 5) << 2) | d31;
#pragma unroll
        for (int i = 0; i < 4; ++i) {
            float4 w0; w0.x = pvC0[i*4+0]; w0.y = pvC0[i*4+1]; w0.z = pvC0[i*4+2]; w0.w = pvC0[i*4+3];
            *(float4*)&RED[0][wid][slot][i * 4] = w0;
            float4 w1; w1.x = pvC1[i*4+0]; w1.y = pvC1[i*4+1]; w1.z = pvC1[i*4+2]; w1.w = pvC1[i*4+3];
            *(float4*)&RED[1][wid][slot][i * 4] = w1;
        }
    }
    __syncthreads();

    if (wid < 2 && lane < 32) {
        const int head = wid;
        const int hh   = head ? h1 : h0;
        const float* wvp = Wv + hh * 9;   // wave-uniform scalar loads
        const int qrow = lane;
        const int hh2 = (qrow >> 2) & 1;
        const int r   = (qrow & 3) | ((qrow >> 3) << 2);
        float acc[4];
#pragma unroll
        for (int d = 0; d < 4; ++d)
            acc[d] = (RED[head][0][hh2 * 4 + d][r] + RED[head][1][hh2 * 4 + d][r])
                   + (RED[head][2][hh2 * 4 + d][r] + RED[head][3][hh2 * 4 + d][r]);
        const float inv = 1.0f / fmaxf(acc[3], 1e-37f);
        const float r0 = acc[0] * inv, r1 = acc[1] * inv, r2 = acc[2] * inv;
        const float o0 = r0 * wvp[0] + r1 * wvp[3] + r2 * wvp[6];
        const float o1 = r0 * wvp[1] + r1 * wvp[4] + r2 * wvp[7];
        const float o2 = r0 * wvp[2] + r1 * wvp[5] + r2 * wvp[8];
        const int bhO = b * NH + hh;
        const int o   = bhO * (SEQ * 3) + (qb * 32 + qrow) * 3;
        const int second = NB * NH * SEQ * 3;
        out[o + 0] = o0; out[o + 1] = o1; out[o + 2] = o2;
        out[o + second + 0] = o0; out[o + second + 1] = o1; out[o + second + 2] = o2;
    }
}

extern "C" void kernel_launch(void* const* d_in, const int* in_sizes, int n_in,
                              void* d_out, int out_size, void* d_ws, size_t ws_size,
                              hipStream_t stream) {
    const float* x  = (const float*)d_in[0];
    const float* Wq = (const float*)d_in[1];
    const float* Wk = (const float*)d_in[2];
    const float* Wv = (const float*)d_in[3];
    float* out = (float*)d_out;
    (void)in_sizes; (void)n_in; (void)d_ws; (void)ws_size; (void)out_size;

    const int grid = NB * (NH / 2) * (SEQ / 32);  // 1024 blocks, 2 heads each
    attn_mfma<<<grid, 256, 0, stream>>>(x, Wq, Wk, Wv, out);
}

// Round 15
// 22.226 us; speedup vs baseline: 1.1754x; 1.0719x over previous
//
#include <hip/hip_runtime.h>

#define SEQ 2048
#define NH 8
#define NB 4

typedef unsigned int u32;
typedef short bf16x8_t __attribute__((ext_vector_type(8)));
typedef float f32x16_t __attribute__((ext_vector_type(16)));

// pack 2 f32 -> 2 bf16, round-half-up (proven R7-R13)
__device__ __forceinline__ u32 pkb(float a, float b) {
    const u32 ua = __builtin_bit_cast(u32, a) + 0x8000u;
    const u32 ub = __builtin_bit_cast(u32, b) + 0x8000u;
    return __builtin_amdgcn_perm(ub, ua, 0x07060302u);  // {a.bf16, b.bf16}
}
// Schraudolph: f32 bit-pattern of ~2^s  (s in [-120,120]); fma + cvt, full-rate VALU
__device__ __forceinline__ u32 e2b(float s) {
    const float F = __builtin_fmaf(s, 8388608.f, 1065353216.f);  // s*2^23 + 127<<23
    return (u32)F;                                               // v_cvt_u32_f32
}
// {bf16(2^a) in low16, bf16(2^b) in high16}: 2x(fma+cvt) + 1 perm
__device__ __forceinline__ u32 pk2(float a, float b) {
    return __builtin_amdgcn_perm(e2b(b), e2b(a), 0x07060302u);
}

union UBv { bf16x8_t v; u32 u[4]; };

__global__ __launch_bounds__(256)   // NOTE: never add min-waves here (R4/R5/R14 NaN)
void attn_mfma(const float* __restrict__ x, const float* __restrict__ Wq,
               const float* __restrict__ Wk, const float* __restrict__ Wv,
               float* __restrict__ out) {
    // VT4: [kt=128][d=4][pos=16] bf16; rows d={x0,x1,x2,ones}; key m at pos pi(m)
    //      (pi = bit2<->bit3 swap). Serves PV-B (2x b128 broadcast reads). 16 KB
    // RED: [head][wid][slot][16] cross-wave partials                        4 KB
    __shared__ __align__(16) char VT4[128 * 128];
    __shared__ __align__(16) float RED[2][4][8][16];

    const int tid = threadIdx.x;
    const int blk = blockIdx.x;
    const int qb   = blk & 63;     // 32-query tile
    const int rest = blk >> 6;
    const int hp   = rest & 3;     // head pair
    const int b    = rest >> 2;
    const int h0   = hp * 2, h1 = h0 + 1;

    const float* xb = x + b * SEQ * 3;

    const int lane = tid & 63;
    const int wid  = tid >> 6;    // k-split: 512 keys per wave
    const int ql   = lane & 31;
    const int q    = qb * 32 + ql;
    const int kbase = wid * 512;

    // ---- A-fragments -> registers (proven R13): lane's own key, 16 tiles ----
    float ax0[16], ax1[16], ax2[16];
#pragma unroll
    for (int t = 0; t < 16; ++t) {
        const float* kp = xb + (kbase + t * 32 + ql) * 3;
        ax0[t] = kp[0]; ax1[t] = kp[1]; ax2[t] = kp[2];
    }

    // ---- staging: 8 keys per thread into VT4, pi-permuted positions ----
    {
        const float4* xg = (const float4*)xb;
        float xv[24];
        const float4 t0 = xg[tid * 6 + 0]; xv[0]=t0.x; xv[1]=t0.y; xv[2]=t0.z; xv[3]=t0.w;
        const float4 t1 = xg[tid * 6 + 1]; xv[4]=t1.x; xv[5]=t1.y; xv[6]=t1.z; xv[7]=t1.w;
        const float4 t2 = xg[tid * 6 + 2]; xv[8]=t2.x; xv[9]=t2.y; xv[10]=t2.z; xv[11]=t2.w;
        const float4 t3 = xg[tid * 6 + 3]; xv[12]=t3.x; xv[13]=t3.y; xv[14]=t3.z; xv[15]=t3.w;
        const float4 t4 = xg[tid * 6 + 4]; xv[16]=t4.x; xv[17]=t4.y; xv[18]=t4.z; xv[19]=t4.w;
        const float4 t5 = xg[tid * 6 + 5]; xv[20]=t5.x; xv[21]=t5.y; xv[22]=t5.z; xv[23]=t5.w;
        const int kt   = tid >> 1;
        const int half = tid & 1;
        const int slotA = half * 4;
        char* base = VT4 + kt * 128;
#pragma unroll
        for (int d = 0; d < 3; ++d) {
            uint2 wa, wb;
            wa.x = pkb(xv[0 + d],  xv[3 + d]);
            wa.y = pkb(xv[6 + d],  xv[9 + d]);
            wb.x = pkb(xv[12 + d], xv[15 + d]);
            wb.y = pkb(xv[18 + d], xv[21 + d]);
            *(uint2*)(base + d * 32 + slotA * 2)      = wa;
            *(uint2*)(base + d * 32 + slotA * 2 + 16) = wb;
        }
        uint4 ones; ones.x = ones.y = ones.z = ones.w = 0x3F803F80u;
        *(uint4*)(base + 96 + half * 16) = ones;
    }

    // pack A-frag registers
    u32 A0[16], A1[16];
#pragma unroll
    for (int t = 0; t < 16; ++t) {
        A0[t] = pkb(ax0[t], ax1[t]);
        A1[t] = pkb(ax2[t], 0.f);
    }

    // u-vectors for BOTH heads (wave-uniform weight scalar loads)
    const float* gq = xb + q * 3;
    const float xq0 = gq[0], xq1 = gq[1], xq2 = gq[2];
    const float cc = 0.5773502691896258f * 1.4426950408889634f;
    float u00, u01, u02, u10, u11, u12;
    {
        const float* wqp = Wq + h0 * 9; const float* wkp = Wk + h0 * 9;
        const float Q0 = xq0 * wqp[0] + xq1 * wqp[3] + xq2 * wqp[6];
        const float Q1 = xq0 * wqp[1] + xq1 * wqp[4] + xq2 * wqp[7];
        const float Q2 = xq0 * wqp[2] + xq1 * wqp[5] + xq2 * wqp[8];
        u00 = (Q0 * wkp[0] + Q1 * wkp[1] + Q2 * wkp[2]) * cc;
        u01 = (Q0 * wkp[3] + Q1 * wkp[4] + Q2 * wkp[5]) * cc;
        u02 = (Q0 * wkp[6] + Q1 * wkp[7] + Q2 * wkp[8]) * cc;
    }
    {
        const float* wqp = Wq + h1 * 9; const float* wkp = Wk + h1 * 9;
        const float Q0 = xq0 * wqp[0] + xq1 * wqp[3] + xq2 * wqp[6];
        const float Q1 = xq0 * wqp[1] + xq1 * wqp[4] + xq2 * wqp[7];
        const float Q2 = xq0 * wqp[2] + xq1 * wqp[5] + xq2 * wqp[8];
        u10 = (Q0 * wkp[0] + Q1 * wkp[1] + Q2 * wkp[2]) * cc;
        u11 = (Q0 * wkp[3] + Q1 * wkp[4] + Q2 * wkp[5]) * cc;
        u12 = (Q0 * wkp[6] + Q1 * wkp[7] + Q2 * wkp[8]) * cc;
    }

    __syncthreads();

    // scores-mfma B operands (k rows >= 4 zero; lanes>=32 all zero)
    UBv Bs0, Bs1;
    Bs0.u[0] = (lane < 32) ? pkb(u00, u01) : 0u;
    Bs0.u[1] = (lane < 32) ? pkb(u02, 0.f) : 0u;
    Bs0.u[2] = 0u; Bs0.u[3] = 0u;
    Bs1.u[0] = (lane < 32) ? pkb(u10, u11) : 0u;
    Bs1.u[1] = (lane < 32) ? pkb(u12, 0.f) : 0u;
    Bs1.u[2] = 0u; Bs1.u[3] = 0u;

    // PV-B address (proven R11-R13)
    const char* vb = VT4 + wid * 4096 + (lane & 3) * 32 + (lane >> 5) * 16;

    f32x16_t pvC0 = {};
    f32x16_t pvC1 = {};
    f32x16_t zc   = {};

    // ---- main loop: 16 k-tiles of 32 keys, 2 heads; 2 ds ops/tile; no trans ops ----
#pragma unroll
    for (int t = 0; t < 16; ++t) {
        const uint4 bv0 = *(const uint4*)(vb + t * 256);
        const uint4 bv1 = *(const uint4*)(vb + t * 256 + 128);
        UBv B0; B0.u[0] = bv0.x; B0.u[1] = bv0.y; B0.u[2] = bv0.z; B0.u[3] = bv0.w;
        UBv B1; B1.u[0] = bv1.x; B1.u[1] = bv1.y; B1.u[2] = bv1.z; B1.u[3] = bv1.w;

        UBv A; A.u[0] = A0[t]; A.u[1] = A1[t]; A.u[2] = 0u; A.u[3] = 0u;
        const f32x16_t sc0 = __builtin_amdgcn_mfma_f32_32x32x16_bf16(A.v, Bs0.v, zc, 0, 0, 0);
        const f32x16_t sc1 = __builtin_amdgcn_mfma_f32_32x32x16_bf16(A.v, Bs1.v, zc, 0, 0, 0);

        // head0
        {
            UBv PA;
            PA.u[0] = pk2(sc0[0],  sc0[1]);
            PA.u[1] = pk2(sc0[2],  sc0[3]);
            PA.u[2] = pk2(sc0[4],  sc0[5]);
            PA.u[3] = pk2(sc0[6],  sc0[7]);
            pvC0 = __builtin_amdgcn_mfma_f32_32x32x16_bf16(PA.v, B0.v, pvC0, 0, 0, 0);
            UBv PB;
            PB.u[0] = pk2(sc0[8],  sc0[9]);
            PB.u[1] = pk2(sc0[10], sc0[11]);
            PB.u[2] = pk2(sc0[12], sc0[13]);
            PB.u[3] = pk2(sc0[14], sc0[15]);
            pvC0 = __builtin_amdgcn_mfma_f32_32x32x16_bf16(PB.v, B1.v, pvC0, 0, 0, 0);
        }
        // head1
        {
            UBv PA;
            PA.u[0] = pk2(sc1[0],  sc1[1]);
            PA.u[1] = pk2(sc1[2],  sc1[3]);
            PA.u[2] = pk2(sc1[4],  sc1[5]);
            PA.u[3] = pk2(sc1[6],  sc1[7]);
            pvC1 = __builtin_amdgcn_mfma_f32_32x32x16_bf16(PA.v, B0.v, pvC1, 0, 0, 0);
            UBv PB;
            PB.u[0] = pk2(sc1[8],  sc1[9]);
            PB.u[1] = pk2(sc1[10], sc1[11]);
            PB.u[2] = pk2(sc1[12], sc1[13]);
            PB.u[3] = pk2(sc1[14], sc1[15]);
            pvC1 = __builtin_amdgcn_mfma_f32_32x32x16_bf16(PB.v, B1.v, pvC1, 0, 0, 0);
        }
    }

    // ---- merge 4 k-splits + epilogue (both heads) ----
    const int d31 = lane & 31;
    if (d31 < 4) {
        const int slot = ((lane >> 5) << 2) | d31;
#pragma unroll
        for (int i = 0; i < 4; ++i) {
            float4 w0; w0.x = pvC0[i*4+0]; w0.y = pvC0[i*4+1]; w0.z = pvC0[i*4+2]; w0.w = pvC0[i*4+3];
            *(float4*)&RED[0][wid][slot][i * 4] = w0;
            float4 w1; w1.x = pvC1[i*4+0]; w1.y = pvC1[i*4+1]; w1.z = pvC1[i*4+2]; w1.w = pvC1[i*4+3];
            *(float4*)&RED[1][wid][slot][i * 4] = w1;
        }
    }
    __syncthreads();

    if (wid < 2 && lane < 32) {
        const int head = wid;
        const int hh   = head ? h1 : h0;
        const float* wvp = Wv + hh * 9;   // wave-uniform scalar loads
        const int qrow = lane;
        const int hh2 = (qrow >> 2) & 1;
        const int r   = (qrow & 3) | ((qrow >> 3) << 2);
        float acc[4];
#pragma unroll
        for (int d = 0; d < 4; ++d)
            acc[d] = (RED[head][0][hh2 * 4 + d][r] + RED[head][1][hh2 * 4 + d][r])
                   + (RED[head][2][hh2 * 4 + d][r] + RED[head][3][hh2 * 4 + d][r]);
        const float inv = 1.0f / fmaxf(acc[3], 1e-37f);
        const float r0 = acc[0] * inv, r1 = acc[1] * inv, r2 = acc[2] * inv;
        const float o0 = r0 * wvp[0] + r1 * wvp[3] + r2 * wvp[6];
        const float o1 = r0 * wvp[1] + r1 * wvp[4] + r2 * wvp[7];
        const float o2 = r0 * wvp[2] + r1 * wvp[5] + r2 * wvp[8];
        const int bhO = b * NH + hh;
        const int o   = bhO * (SEQ * 3) + (qb * 32 + qrow) * 3;
        const int second = NB * NH * SEQ * 3;
        out[o + 0] = o0; out[o + 1] = o1; out[o + 2] = o2;
        out[o + second + 0] = o0; out[o + second + 1] = o1; out[o + second + 2] = o2;
    }
}

extern "C" void kernel_launch(void* const* d_in, const int* in_sizes, int n_in,
                              void* d_out, int out_size, void* d_ws, size_t ws_size,
                              hipStream_t stream) {
    const float* x  = (const float*)d_in[0];
    const float* Wq = (const float*)d_in[1];
    const float* Wk = (const float*)d_in[2];
    const float* Wv = (const float*)d_in[3];
    float* out = (float*)d_out;
    (void)in_sizes; (void)n_in; (void)d_ws; (void)ws_size; (void)out_size;

    const int grid = NB * (NH / 2) * (SEQ / 32);  // 1024 blocks, 2 heads each
    attn_mfma<<<grid, 256, 0, stream>>>(x, Wq, Wk, Wv, out);
}

// Round 16
// 21.828 us; speedup vs baseline: 1.1968x; 1.0182x over previous
//
#include <hip/hip_runtime.h>

#define SEQ 2048
#define NH 8
#define NB 4

typedef unsigned int u32;
typedef short bf16x8_t __attribute__((ext_vector_type(8)));
typedef float f32x16_t __attribute__((ext_vector_type(16)));

// pack 2 f32 -> 2 bf16, round-half-up (proven R7-R15)
__device__ __forceinline__ u32 pkb(float a, float b) {
    const u32 ua = __builtin_bit_cast(u32, a) + 0x8000u;
    const u32 ub = __builtin_bit_cast(u32, b) + 0x8000u;
    return __builtin_amdgcn_perm(ub, ua, 0x07060302u);  // {a.bf16, b.bf16}
}
// sc already = s*2^23 + 127*2^23 (bias folded into MFMA C). Top 16 bits of the
// integer value ARE bf16(2^s). One cvt per score + one perm per pair.
__device__ __forceinline__ u32 pks(float Fa, float Fb) {
    const u32 ia = (u32)Fa;   // v_cvt_u32_f32 (RTZ, clamps <0 to 0 -> p=0, benign)
    const u32 ib = (u32)Fb;
    return __builtin_amdgcn_perm(ib, ia, 0x07060302u);  // {ia.hi16, ib.hi16}
}

union UBv { bf16x8_t v; u32 u[4]; };

__global__ __launch_bounds__(256)   // NOTE: never add min-waves (R4/R5/R14 NaN)
void attn_mfma(const float* __restrict__ x, const float* __restrict__ Wq,
               const float* __restrict__ Wk, const float* __restrict__ Wv,
               float* __restrict__ out) {
    // VT4: [kt=128][d=4][pos=16] bf16; rows d={x0,x1,x2,ones}; key m at pos pi(m)
    //      (pi = bit2<->bit3 swap). Serves PV-B (2x b128 broadcast reads). 16 KB
    // RED: [head][wid][slot][16] cross-wave partials                        4 KB
    __shared__ __align__(16) char VT4[128 * 128];
    __shared__ __align__(16) float RED[2][4][8][16];

    const int tid = threadIdx.x;
    const int blk = blockIdx.x;
    const int qb   = blk & 63;     // 32-query tile
    const int rest = blk >> 6;
    const int hp   = rest & 3;     // head pair
    const int b    = rest >> 2;
    const int h0   = hp * 2, h1 = h0 + 1;

    const float* xb = x + b * SEQ * 3;

    const int lane = tid & 63;
    const int wid  = tid >> 6;    // k-split: 512 keys per wave
    const int ql   = lane & 31;
    const int q    = qb * 32 + ql;
    const int kbase = wid * 512;

    // ---- A-fragments -> registers (proven R13/R15): lane's own key, 16 tiles ----
    float ax0[16], ax1[16], ax2[16];
#pragma unroll
    for (int t = 0; t < 16; ++t) {
        const float* kp = xb + (kbase + t * 32 + ql) * 3;
        ax0[t] = kp[0]; ax1[t] = kp[1]; ax2[t] = kp[2];
    }

    // ---- staging: 8 keys per thread into VT4, pi-permuted positions ----
    {
        const float4* xg = (const float4*)xb;
        float xv[24];
        const float4 t0 = xg[tid * 6 + 0]; xv[0]=t0.x; xv[1]=t0.y; xv[2]=t0.z; xv[3]=t0.w;
        const float4 t1 = xg[tid * 6 + 1]; xv[4]=t1.x; xv[5]=t1.y; xv[6]=t1.z; xv[7]=t1.w;
        const float4 t2 = xg[tid * 6 + 2]; xv[8]=t2.x; xv[9]=t2.y; xv[10]=t2.z; xv[11]=t2.w;
        const float4 t3 = xg[tid * 6 + 3]; xv[12]=t3.x; xv[13]=t3.y; xv[14]=t3.z; xv[15]=t3.w;
        const float4 t4 = xg[tid * 6 + 4]; xv[16]=t4.x; xv[17]=t4.y; xv[18]=t4.z; xv[19]=t4.w;
        const float4 t5 = xg[tid * 6 + 5]; xv[20]=t5.x; xv[21]=t5.y; xv[22]=t5.z; xv[23]=t5.w;
        const int kt   = tid >> 1;
        const int half = tid & 1;
        const int slotA = half * 4;
        char* base = VT4 + kt * 128;
#pragma unroll
        for (int d = 0; d < 3; ++d) {
            uint2 wa, wb;
            wa.x = pkb(xv[0 + d],  xv[3 + d]);
            wa.y = pkb(xv[6 + d],  xv[9 + d]);
            wb.x = pkb(xv[12 + d], xv[15 + d]);
            wb.y = pkb(xv[18 + d], xv[21 + d]);
            *(uint2*)(base + d * 32 + slotA * 2)      = wa;
            *(uint2*)(base + d * 32 + slotA * 2 + 16) = wb;
        }
        uint4 ones; ones.x = ones.y = ones.z = ones.w = 0x3F803F80u;
        *(uint4*)(base + 96 + half * 16) = ones;
    }

    // pack A-frag registers
    u32 A0[16], A1[16];
#pragma unroll
    for (int t = 0; t < 16; ++t) {
        A0[t] = pkb(ax0[t], ax1[t]);
        A1[t] = pkb(ax2[t], 0.f);
    }

    // u-vectors for BOTH heads, PRE-SCALED by 2^23 (Schraudolph fma folded into MFMA)
    const float* gq = xb + q * 3;
    const float xq0 = gq[0], xq1 = gq[1], xq2 = gq[2];
    const float cc = 0.5773502691896258f * 1.4426950408889634f * 8388608.0f;
    float u00, u01, u02, u10, u11, u12;
    {
        const float* wqp = Wq + h0 * 9; const float* wkp = Wk + h0 * 9;
        const float Q0 = xq0 * wqp[0] + xq1 * wqp[3] + xq2 * wqp[6];
        const float Q1 = xq0 * wqp[1] + xq1 * wqp[4] + xq2 * wqp[7];
        const float Q2 = xq0 * wqp[2] + xq1 * wqp[5] + xq2 * wqp[8];
        u00 = (Q0 * wkp[0] + Q1 * wkp[1] + Q2 * wkp[2]) * cc;
        u01 = (Q0 * wkp[3] + Q1 * wkp[4] + Q2 * wkp[5]) * cc;
        u02 = (Q0 * wkp[6] + Q1 * wkp[7] + Q2 * wkp[8]) * cc;
    }
    {
        const float* wqp = Wq + h1 * 9; const float* wkp = Wk + h1 * 9;
        const float Q0 = xq0 * wqp[0] + xq1 * wqp[3] + xq2 * wqp[6];
        const float Q1 = xq0 * wqp[1] + xq1 * wqp[4] + xq2 * wqp[7];
        const float Q2 = xq0 * wqp[2] + xq1 * wqp[5] + xq2 * wqp[8];
        u10 = (Q0 * wkp[0] + Q1 * wkp[1] + Q2 * wkp[2]) * cc;
        u11 = (Q0 * wkp[3] + Q1 * wkp[4] + Q2 * wkp[5]) * cc;
        u12 = (Q0 * wkp[6] + Q1 * wkp[7] + Q2 * wkp[8]) * cc;
    }

    __syncthreads();

    // scores-mfma B operands (k rows >= 4 zero; lanes>=32 all zero)
    UBv Bs0, Bs1;
    Bs0.u[0] = (lane < 32) ? pkb(u00, u01) : 0u;
    Bs0.u[1] = (lane < 32) ? pkb(u02, 0.f) : 0u;
    Bs0.u[2] = 0u; Bs0.u[3] = 0u;
    Bs1.u[0] = (lane < 32) ? pkb(u10, u11) : 0u;
    Bs1.u[1] = (lane < 32) ? pkb(u12, 0.f) : 0u;
    Bs1.u[2] = 0u; Bs1.u[3] = 0u;

    // PV-B address (proven R11-R15)
    const char* vb = VT4 + wid * 4096 + (lane & 3) * 32 + (lane >> 5) * 16;

    f32x16_t pvC0 = {};
    f32x16_t pvC1 = {};
    f32x16_t bc;                       // Schraudolph bias as MFMA C-operand
#pragma unroll
    for (int i = 0; i < 16; ++i) bc[i] = 1065353216.0f;   // 127 << 23

    // ---- main loop: 16 k-tiles, 2 heads; 2 ds ops/tile; 1 cvt + 0.5 perm per score ----
#pragma unroll
    for (int t = 0; t < 16; ++t) {
        const uint4 bv0 = *(const uint4*)(vb + t * 256);
        const uint4 bv1 = *(const uint4*)(vb + t * 256 + 128);
        UBv B0; B0.u[0] = bv0.x; B0.u[1] = bv0.y; B0.u[2] = bv0.z; B0.u[3] = bv0.w;
        UBv B1; B1.u[0] = bv1.x; B1.u[1] = bv1.y; B1.u[2] = bv1.z; B1.u[3] = bv1.w;

        UBv A; A.u[0] = A0[t]; A.u[1] = A1[t]; A.u[2] = 0u; A.u[3] = 0u;
        const f32x16_t sc0 = __builtin_amdgcn_mfma_f32_32x32x16_bf16(A.v, Bs0.v, bc, 0, 0, 0);
        const f32x16_t sc1 = __builtin_amdgcn_mfma_f32_32x32x16_bf16(A.v, Bs1.v, bc, 0, 0, 0);

        // head0
        {
            UBv PA;
            PA.u[0] = pks(sc0[0],  sc0[1]);
            PA.u[1] = pks(sc0[2],  sc0[3]);
            PA.u[2] = pks(sc0[4],  sc0[5]);
            PA.u[3] = pks(sc0[6],  sc0[7]);
            pvC0 = __builtin_amdgcn_mfma_f32_32x32x16_bf16(PA.v, B0.v, pvC0, 0, 0, 0);
            UBv PB;
            PB.u[0] = pks(sc0[8],  sc0[9]);
            PB.u[1] = pks(sc0[10], sc0[11]);
            PB.u[2] = pks(sc0[12], sc0[13]);
            PB.u[3] = pks(sc0[14], sc0[15]);
            pvC0 = __builtin_amdgcn_mfma_f32_32x32x16_bf16(PB.v, B1.v, pvC0, 0, 0, 0);
        }
        // head1
        {
            UBv PA;
            PA.u[0] = pks(sc1[0],  sc1[1]);
            PA.u[1] = pks(sc1[2],  sc1[3]);
            PA.u[2] = pks(sc1[4],  sc1[5]);
            PA.u[3] = pks(sc1[6],  sc1[7]);
            pvC1 = __builtin_amdgcn_mfma_f32_32x32x16_bf16(PA.v, B0.v, pvC1, 0, 0, 0);
            UBv PB;
            PB.u[0] = pks(sc1[8],  sc1[9]);
            PB.u[1] = pks(sc1[10], sc1[11]);
            PB.u[2] = pks(sc1[12], sc1[13]);
            PB.u[3] = pks(sc1[14], sc1[15]);
            pvC1 = __builtin_amdgcn_mfma_f32_32x32x16_bf16(PB.v, B1.v, pvC1, 0, 0, 0);
        }
    }

    // ---- merge 4 k-splits + epilogue (both heads) ----
    const int d31 = lane & 31;
    if (d31 < 4) {
        const int slot = ((lane >> 5) << 2) | d31;
#pragma unroll
        for (int i = 0; i < 4; ++i) {
            float4 w0; w0.x = pvC0[i*4+0]; w0.y = pvC0[i*4+1]; w0.z = pvC0[i*4+2]; w0.w = pvC0[i*4+3];
            *(float4*)&RED[0][wid][slot][i * 4] = w0;
            float4 w1; w1.x = pvC1[i*4+0]; w1.y = pvC1[i*4+1]; w1.z = pvC1[i*4+2]; w1.w = pvC1[i*4+3];
            *(float4*)&RED[1][wid][slot][i * 4] = w1;
        }
    }
    __syncthreads();

    if (wid < 2 && lane < 32) {
        const int head = wid;
        const int hh   = head ? h1 : h0;
        const float* wvp = Wv + hh * 9;   // wave-uniform scalar loads
        const int qrow = lane;
        const int hh2 = (qrow >> 2) & 1;
        const int r   = (qrow & 3) | ((qrow >> 3) << 2);
        float acc[4];
#pragma unroll
        for (int d = 0; d < 4; ++d)
            acc[d] = (RED[head][0][hh2 * 4 + d][r] + RED[head][1][hh2 * 4 + d][r])
                   + (RED[head][2][hh2 * 4 + d][r] + RED[head][3][hh2 * 4 + d][r]);
        const float inv = 1.0f / fmaxf(acc[3], 1e-37f);
        const float r0 = acc[0] * inv, r1 = acc[1] * inv, r2 = acc[2] * inv;
        const float o0 = r0 * wvp[0] + r1 * wvp[3] + r2 * wvp[6];
        const float o1 = r0 * wvp[1] + r1 * wvp[4] + r2 * wvp[7];
        const float o2 = r0 * wvp[2] + r1 * wvp[5] + r2 * wvp[8];
        const int bhO = b * NH + hh;
        const int o   = bhO * (SEQ * 3) + (qb * 32 + qrow) * 3;
        const int second = NB * NH * SEQ * 3;
        out[o + 0] = o0; out[o + 1] = o1; out[o + 2] = o2;
        out[o + second + 0] = o0; out[o + second + 1] = o1; out[o + second + 2] = o2;
    }
}

extern "C" void kernel_launch(void* const* d_in, const int* in_sizes, int n_in,
                              void* d_out, int out_size, void* d_ws, size_t ws_size,
                              hipStream_t stream) {
    const float* x  = (const float*)d_in[0];
    const float* Wq = (const float*)d_in[1];
    const float* Wk = (const float*)d_in[2];
    const float* Wv = (const float*)d_in[3];
    float* out = (float*)d_out;
    (void)in_sizes; (void)n_in; (void)d_ws; (void)ws_size; (void)out_size;

    const int grid = NB * (NH / 2) * (SEQ / 32);  // 1024 blocks, 2 heads each
    attn_mfma<<<grid, 256, 0, stream>>>(x, Wq, Wk, Wv, out);
}

// Round 17
// 20.427 us; speedup vs baseline: 1.2789x; 1.0686x over previous
//
#include <hip/hip_runtime.h>

#define SEQ 2048
#define NH 8
#define NB 4

typedef unsigned int u32;
typedef short bf16x8_t __attribute__((ext_vector_type(8)));
typedef float f32x16_t __attribute__((ext_vector_type(16)));

// pack 2 f32 -> 2 bf16, round-half-up (proven R7-R16)
__device__ __forceinline__ u32 pkb(float a, float b) {
    const u32 ua = __builtin_bit_cast(u32, a) + 0x8000u;
    const u32 ub = __builtin_bit_cast(u32, b) + 0x8000u;
    return __builtin_amdgcn_perm(ub, ua, 0x07060302u);  // {a.bf16, b.bf16}
}
// sc = s*2^23 + 127*2^23 (bias in MFMA C). Top 16 bits of (u32)sc ARE bf16(2^s).
__device__ __forceinline__ u32 pks(float Fa, float Fb) {
    const u32 ia = (u32)Fa;   // v_cvt_u32_f32 (clamps <0 to 0 -> p=0, benign)
    const u32 ib = (u32)Fb;
    return __builtin_amdgcn_perm(ib, ia, 0x07060302u);  // {ia.hi16, ib.hi16}
}

union UBv { bf16x8_t v; u32 u[4]; };

__global__ __launch_bounds__(256)   // NOTE: never add min-waves (R4/R5/R14 NaN)
void attn_mfma(const float* __restrict__ x, const float* __restrict__ Wq,
               const float* __restrict__ Wk, const float* __restrict__ Wv,
               float* __restrict__ out) {
    // VT4: [kt=128][d=4][pos=16] bf16; rows d={x0,x1,x2,ones}; key m at pos pi(m)
    //      (pi = bit2<->bit3 swap). Serves PV-B (2x b128 broadcast reads). 16 KB
    // RED: [head][wid][slot][16] cross-wave partials                        4 KB
    __shared__ __align__(16) char VT4[128 * 128];
    __shared__ __align__(16) float RED[2][4][8][16];

    const int tid = threadIdx.x;
    const int blk = blockIdx.x;
    const int qb   = blk & 63;     // 32-query tile
    const int rest = blk >> 6;
    const int hp   = rest & 3;     // head pair
    const int b    = rest >> 2;
    const int h0   = hp * 2, h1 = h0 + 1;

    const float* xb = x + b * SEQ * 3;

    const int lane = tid & 63;
    const int wid  = tid >> 6;    // k-split: 512 keys per wave
    const int ql   = lane & 31;
    const int q    = qb * 32 + ql;
    const int kbase = wid * 512;

    // ---- A-fragments -> registers (proven R13/R15/R16): lane's own key ----
    float ax0[16], ax1[16], ax2[16];
#pragma unroll
    for (int t = 0; t < 16; ++t) {
        const float* kp = xb + (kbase + t * 32 + ql) * 3;
        ax0[t] = kp[0]; ax1[t] = kp[1]; ax2[t] = kp[2];
    }

    // ---- staging: 8 keys per thread into VT4, pi-permuted positions ----
    {
        const float4* xg = (const float4*)xb;
        float xv[24];
        const float4 t0 = xg[tid * 6 + 0]; xv[0]=t0.x; xv[1]=t0.y; xv[2]=t0.z; xv[3]=t0.w;
        const float4 t1 = xg[tid * 6 + 1]; xv[4]=t1.x; xv[5]=t1.y; xv[6]=t1.z; xv[7]=t1.w;
        const float4 t2 = xg[tid * 6 + 2]; xv[8]=t2.x; xv[9]=t2.y; xv[10]=t2.z; xv[11]=t2.w;
        const float4 t3 = xg[tid * 6 + 3]; xv[12]=t3.x; xv[13]=t3.y; xv[14]=t3.z; xv[15]=t3.w;
        const float4 t4 = xg[tid * 6 + 4]; xv[16]=t4.x; xv[17]=t4.y; xv[18]=t4.z; xv[19]=t4.w;
        const float4 t5 = xg[tid * 6 + 5]; xv[20]=t5.x; xv[21]=t5.y; xv[22]=t5.z; xv[23]=t5.w;
        const int kt   = tid >> 1;
        const int half = tid & 1;
        const int slotA = half * 4;
        char* base = VT4 + kt * 128;
#pragma unroll
        for (int d = 0; d < 3; ++d) {
            uint2 wa, wb;
            wa.x = pkb(xv[0 + d],  xv[3 + d]);
            wa.y = pkb(xv[6 + d],  xv[9 + d]);
            wb.x = pkb(xv[12 + d], xv[15 + d]);
            wb.y = pkb(xv[18 + d], xv[21 + d]);
            *(uint2*)(base + d * 32 + slotA * 2)      = wa;
            *(uint2*)(base + d * 32 + slotA * 2 + 16) = wb;
        }
        uint4 ones; ones.x = ones.y = ones.z = ones.w = 0x3F803F80u;
        *(uint4*)(base + 96 + half * 16) = ones;
    }

    // pack A-frag registers
    u32 A0[16], A1[16];
#pragma unroll
    for (int t = 0; t < 16; ++t) {
        A0[t] = pkb(ax0[t], ax1[t]);
        A1[t] = pkb(ax2[t], 0.f);
    }

    // u-vectors for BOTH heads, PRE-SCALED by 2^23 (Schraudolph fold, proven R16)
    const float* gq = xb + q * 3;
    const float xq0 = gq[0], xq1 = gq[1], xq2 = gq[2];
    const float cc = 0.5773502691896258f * 1.4426950408889634f * 8388608.0f;
    float u00, u01, u02, u10, u11, u12;
    {
        const float* wqp = Wq + h0 * 9; const float* wkp = Wk + h0 * 9;
        const float Q0 = xq0 * wqp[0] + xq1 * wqp[3] + xq2 * wqp[6];
        const float Q1 = xq0 * wqp[1] + xq1 * wqp[4] + xq2 * wqp[7];
        const float Q2 = xq0 * wqp[2] + xq1 * wqp[5] + xq2 * wqp[8];
        u00 = (Q0 * wkp[0] + Q1 * wkp[1] + Q2 * wkp[2]) * cc;
        u01 = (Q0 * wkp[3] + Q1 * wkp[4] + Q2 * wkp[5]) * cc;
        u02 = (Q0 * wkp[6] + Q1 * wkp[7] + Q2 * wkp[8]) * cc;
    }
    {
        const float* wqp = Wq + h1 * 9; const float* wkp = Wk + h1 * 9;
        const float Q0 = xq0 * wqp[0] + xq1 * wqp[3] + xq2 * wqp[6];
        const float Q1 = xq0 * wqp[1] + xq1 * wqp[4] + xq2 * wqp[7];
        const float Q2 = xq0 * wqp[2] + xq1 * wqp[5] + xq2 * wqp[8];
        u10 = (Q0 * wkp[0] + Q1 * wkp[1] + Q2 * wkp[2]) * cc;
        u11 = (Q0 * wkp[3] + Q1 * wkp[4] + Q2 * wkp[5]) * cc;
        u12 = (Q0 * wkp[6] + Q1 * wkp[7] + Q2 * wkp[8]) * cc;
    }

    __syncthreads();

    // scores-mfma B operands
    UBv Bs0, Bs1;
    Bs0.u[0] = (lane < 32) ? pkb(u00, u01) : 0u;
    Bs0.u[1] = (lane < 32) ? pkb(u02, 0.f) : 0u;
    Bs0.u[2] = 0u; Bs0.u[3] = 0u;
    Bs1.u[0] = (lane < 32) ? pkb(u10, u11) : 0u;
    Bs1.u[1] = (lane < 32) ? pkb(u12, 0.f) : 0u;
    Bs1.u[2] = 0u; Bs1.u[3] = 0u;

    // PV-B address (proven R11-R16)
    const char* vb = VT4 + wid * 4096 + (lane & 3) * 32 + (lane >> 5) * 16;

    f32x16_t bc;                       // Schraudolph bias as MFMA C-operand
#pragma unroll
    for (int i = 0; i < 16; ++i) bc[i] = 1065353216.0f;   // 127 << 23

    const int d31 = lane & 31;
    const int slot = ((lane >> 5) << 2) | d31;

    // ---- TWO SEQUENTIAL HEAD-PASSES sharing one accumulator (liveness < 128) ----
#pragma unroll
    for (int head = 0; head < 2; ++head) {
        const UBv Bs = head ? Bs1 : Bs0;
        f32x16_t pvC = {};
#pragma unroll
        for (int t = 0; t < 16; ++t) {
            const uint4 bv0 = *(const uint4*)(vb + t * 256);
            const uint4 bv1 = *(const uint4*)(vb + t * 256 + 128);
            UBv B0; B0.u[0] = bv0.x; B0.u[1] = bv0.y; B0.u[2] = bv0.z; B0.u[3] = bv0.w;
            UBv B1; B1.u[0] = bv1.x; B1.u[1] = bv1.y; B1.u[2] = bv1.z; B1.u[3] = bv1.w;

            UBv A; A.u[0] = A0[t]; A.u[1] = A1[t]; A.u[2] = 0u; A.u[3] = 0u;
            const f32x16_t sc = __builtin_amdgcn_mfma_f32_32x32x16_bf16(A.v, Bs.v, bc, 0, 0, 0);

            UBv PA;
            PA.u[0] = pks(sc[0],  sc[1]);
            PA.u[1] = pks(sc[2],  sc[3]);
            PA.u[2] = pks(sc[4],  sc[5]);
            PA.u[3] = pks(sc[6],  sc[7]);
            pvC = __builtin_amdgcn_mfma_f32_32x32x16_bf16(PA.v, B0.v, pvC, 0, 0, 0);
            UBv PB;
            PB.u[0] = pks(sc[8],  sc[9]);
            PB.u[1] = pks(sc[10], sc[11]);
            PB.u[2] = pks(sc[12], sc[13]);
            PB.u[3] = pks(sc[14], sc[15]);
            pvC = __builtin_amdgcn_mfma_f32_32x32x16_bf16(PB.v, B1.v, pvC, 0, 0, 0);
        }
        // dump this head's partials to LDS (kills pvC liveness before next pass)
        if (d31 < 4) {
#pragma unroll
            for (int i = 0; i < 4; ++i) {
                float4 w; w.x = pvC[i*4+0]; w.y = pvC[i*4+1];
                w.z = pvC[i*4+2]; w.w = pvC[i*4+3];
                *(float4*)&RED[head][wid][slot][i * 4] = w;
            }
        }
    }
    __syncthreads();

    // ---- merge 4 k-splits + epilogue (both heads) ----
    if (wid < 2 && lane < 32) {
        const int head = wid;
        const int hh   = head ? h1 : h0;
        const float* wvp = Wv + hh * 9;   // wave-uniform scalar loads
        const int qrow = lane;
        const int hh2 = (qrow >> 2) & 1;
        const int r   = (qrow & 3) | ((qrow >> 3) << 2);
        float acc[4];
#pragma unroll
        for (int d = 0; d < 4; ++d)
            acc[d] = (RED[head][0][hh2 * 4 + d][r] + RED[head][1][hh2 * 4 + d][r])
                   + (RED[head][2][hh2 * 4 + d][r] + RED[head][3][hh2 * 4 + d][r]);
        const float inv = 1.0f / fmaxf(acc[3], 1e-37f);
        const float r0 = acc[0] * inv, r1 = acc[1] * inv, r2 = acc[2] * inv;
        const float o0 = r0 * wvp[0] + r1 * wvp[3] + r2 * wvp[6];
        const float o1 = r0 * wvp[1] + r1 * wvp[4] + r2 * wvp[7];
        const float o2 = r0 * wvp[2] + r1 * wvp[5] + r2 * wvp[8];
        const int bhO = b * NH + hh;
        const int o   = bhO * (SEQ * 3) + (qb * 32 + qrow) * 3;
        const int second = NB * NH * SEQ * 3;
        out[o + 0] = o0; out[o + 1] = o1; out[o + 2] = o2;
        out[o + second + 0] = o0; out[o + second + 1] = o1; out[o + second + 2] = o2;
    }
}

extern "C" void kernel_launch(void* const* d_in, const int* in_sizes, int n_in,
                              void* d_out, int out_size, void* d_ws, size_t ws_size,
                              hipStream_t stream) {
    const float* x  = (const float*)d_in[0];
    const float* Wq = (const float*)d_in[1];
    const float* Wk = (const float*)d_in[2];
    const float* Wv = (const float*)d_in[3];
    float* out = (float*)d_out;
    (void)in_sizes; (void)n_in; (void)d_ws; (void)ws_size; (void)out_size;

    const int grid = NB * (NH / 2) * (SEQ / 32);  // 1024 blocks, 2 heads each
    attn_mfma<<<grid, 256, 0, stream>>>(x, Wq, Wk, Wv, out);
}

// Round 18
// 18.709 us; speedup vs baseline: 1.3963x; 1.0918x over previous
//
#include <hip/hip_runtime.h>

#define SEQ 2048
#define NH 8
#define NB 4

typedef unsigned int u32;
typedef short bf16x8_t __attribute__((ext_vector_type(8)));
typedef float f32x16_t __attribute__((ext_vector_type(16)));

// pack 2 f32 -> 2 bf16, round-half-up (proven R7-R17) - staging only
__device__ __forceinline__ u32 pkb(float a, float b) {
    const u32 ua = __builtin_bit_cast(u32, a) + 0x8000u;
    const u32 ub = __builtin_bit_cast(u32, b) + 0x8000u;
    return __builtin_amdgcn_perm(ub, ua, 0x07060302u);  // {a.bf16, b.bf16}
}
// sc = s*2^7 + 16256 + 2^23 (bias in MFMA C; f32 in [2^23,2^24) -> mantissa IS the
// integer). bits(sc).lo16 == bf16(2^s). P-pair = ONE v_perm, zero cvt.
__device__ __forceinline__ u32 pks(float Fa, float Fb) {
    return __builtin_amdgcn_perm(__builtin_bit_cast(u32, Fb),
                                 __builtin_bit_cast(u32, Fa), 0x05040100u);
}

union UBv { bf16x8_t v; u32 u[4]; };

__global__ __launch_bounds__(256)   // NOTE: never add min-waves (R4/R5/R14 NaN)
void attn_mfma(const float* __restrict__ x, const float* __restrict__ Wq,
               const float* __restrict__ Wk, const float* __restrict__ Wv,
               float* __restrict__ out) {
    // VT4: [kt=128][d=4][pos=16] bf16; rows d={x0,x1,x2,ones}; key m at pos pi(m)
    //      (pi = bit2<->bit3 swap). Serves PV-B (2x b128 broadcast reads). 16 KB
    // RED: [head][wid][slot][16] cross-wave partials                        4 KB
    __shared__ __align__(16) char VT4[128 * 128];
    __shared__ __align__(16) float RED[2][4][8][16];

    const int tid = threadIdx.x;
    const int blk = blockIdx.x;
    const int qb   = blk & 63;     // 32-query tile
    const int rest = blk >> 6;
    const int hp   = rest & 3;     // head pair
    const int b    = rest >> 2;
    const int h0   = hp * 2, h1 = h0 + 1;

    const float* xb = x + b * SEQ * 3;

    const int lane = tid & 63;
    const int wid  = tid >> 6;    // k-split: 512 keys per wave
    const int ql   = lane & 31;
    const int q    = qb * 32 + ql;
    const int kbase = wid * 512;

    // ---- A-fragments -> registers: lane's own key, 16 tiles ----
    float ax0[16], ax1[16], ax2[16];
#pragma unroll
    for (int t = 0; t < 16; ++t) {
        const float* kp = xb + (kbase + t * 32 + ql) * 3;
        ax0[t] = kp[0]; ax1[t] = kp[1]; ax2[t] = kp[2];
    }

    // ---- staging: 8 keys per thread into VT4, pi-permuted positions ----
    {
        const float4* xg = (const float4*)xb;
        float xv[24];
        const float4 t0 = xg[tid * 6 + 0]; xv[0]=t0.x; xv[1]=t0.y; xv[2]=t0.z; xv[3]=t0.w;
        const float4 t1 = xg[tid * 6 + 1]; xv[4]=t1.x; xv[5]=t1.y; xv[6]=t1.z; xv[7]=t1.w;
        const float4 t2 = xg[tid * 6 + 2]; xv[8]=t2.x; xv[9]=t2.y; xv[10]=t2.z; xv[11]=t2.w;
        const float4 t3 = xg[tid * 6 + 3]; xv[12]=t3.x; xv[13]=t3.y; xv[14]=t3.z; xv[15]=t3.w;
        const float4 t4 = xg[tid * 6 + 4]; xv[16]=t4.x; xv[17]=t4.y; xv[18]=t4.z; xv[19]=t4.w;
        const float4 t5 = xg[tid * 6 + 5]; xv[20]=t5.x; xv[21]=t5.y; xv[22]=t5.z; xv[23]=t5.w;
        const int kt   = tid >> 1;
        const int half = tid & 1;
        const int slotA = half * 4;
        char* base = VT4 + kt * 128;
#pragma unroll
        for (int d = 0; d < 3; ++d) {
            uint2 wa, wb;
            wa.x = pkb(xv[0 + d],  xv[3 + d]);
            wa.y = pkb(xv[6 + d],  xv[9 + d]);
            wb.x = pkb(xv[12 + d], xv[15 + d]);
            wb.y = pkb(xv[18 + d], xv[21 + d]);
            *(uint2*)(base + d * 32 + slotA * 2)      = wa;
            *(uint2*)(base + d * 32 + slotA * 2 + 16) = wb;
        }
        uint4 ones; ones.x = ones.y = ones.z = ones.w = 0x3F803F80u;
        *(uint4*)(base + 96 + half * 16) = ones;
    }

    // pack A-frag registers: A0 full, A1 halves packed 2-tiles-per-reg (-8 VGPR)
    u32 A0[16], A1h[8];
#pragma unroll
    for (int t = 0; t < 16; ++t) A0[t] = pkb(ax0[t], ax1[t]);
#pragma unroll
    for (int j = 0; j < 8; ++j)  A1h[j] = pkb(ax2[2 * j], ax2[2 * j + 1]);

    // u-vectors for BOTH heads, PRE-SCALED by 2^7 (mantissa-trick Schraudolph)
    const float* gq = xb + q * 3;
    const float xq0 = gq[0], xq1 = gq[1], xq2 = gq[2];
    const float cc = 0.5773502691896258f * 1.4426950408889634f * 128.0f;
    float u00, u01, u02, u10, u11, u12;
    {
        const float* wqp = Wq + h0 * 9; const float* wkp = Wk + h0 * 9;
        const float Q0 = xq0 * wqp[0] + xq1 * wqp[3] + xq2 * wqp[6];
        const float Q1 = xq0 * wqp[1] + xq1 * wqp[4] + xq2 * wqp[7];
        const float Q2 = xq0 * wqp[2] + xq1 * wqp[5] + xq2 * wqp[8];
        u00 = (Q0 * wkp[0] + Q1 * wkp[1] + Q2 * wkp[2]) * cc;
        u01 = (Q0 * wkp[3] + Q1 * wkp[4] + Q2 * wkp[5]) * cc;
        u02 = (Q0 * wkp[6] + Q1 * wkp[7] + Q2 * wkp[8]) * cc;
    }
    {
        const float* wqp = Wq + h1 * 9; const float* wkp = Wk + h1 * 9;
        const float Q0 = xq0 * wqp[0] + xq1 * wqp[3] + xq2 * wqp[6];
        const float Q1 = xq0 * wqp[1] + xq1 * wqp[4] + xq2 * wqp[7];
        const float Q2 = xq0 * wqp[2] + xq1 * wqp[5] + xq2 * wqp[8];
        u10 = (Q0 * wkp[0] + Q1 * wkp[1] + Q2 * wkp[2]) * cc;
        u11 = (Q0 * wkp[3] + Q1 * wkp[4] + Q2 * wkp[5]) * cc;
        u12 = (Q0 * wkp[6] + Q1 * wkp[7] + Q2 * wkp[8]) * cc;
    }

    __syncthreads();

    // scores-mfma B operands
    UBv Bs0, Bs1;
    Bs0.u[0] = (lane < 32) ? pkb(u00, u01) : 0u;
    Bs0.u[1] = (lane < 32) ? pkb(u02, 0.f) : 0u;
    Bs0.u[2] = 0u; Bs0.u[3] = 0u;
    Bs1.u[0] = (lane < 32) ? pkb(u10, u11) : 0u;
    Bs1.u[1] = (lane < 32) ? pkb(u12, 0.f) : 0u;
    Bs1.u[2] = 0u; Bs1.u[3] = 0u;

    // PV-B address (proven R11-R17)
    const char* vb = VT4 + wid * 4096 + (lane & 3) * 32 + (lane >> 5) * 16;

    f32x16_t pvC0 = {};
    f32x16_t pvC1 = {};
    f32x16_t bc;                      // mantissa-trick bias as MFMA C-operand
#pragma unroll
    for (int i = 0; i < 16; ++i) bc[i] = 8404864.0f;   // 2^23 + 127*2^7

    // ---- main loop: 16 k-tiles; V-reads SHARED across heads; heads serialized ----
#pragma unroll
    for (int t = 0; t < 16; ++t) {
        const uint4 bv0 = *(const uint4*)(vb + t * 256);
        const uint4 bv1 = *(const uint4*)(vb + t * 256 + 128);
        UBv B0; B0.u[0] = bv0.x; B0.u[1] = bv0.y; B0.u[2] = bv0.z; B0.u[3] = bv0.w;
        UBv B1; B1.u[0] = bv1.x; B1.u[1] = bv1.y; B1.u[2] = bv1.z; B1.u[3] = bv1.w;

        UBv A;
        A.u[0] = A0[t];
        A.u[1] = (t & 1) ? (A1h[t >> 1] >> 16) : (A1h[t >> 1] & 0xFFFFu);
        A.u[2] = 0u; A.u[3] = 0u;

        // head0: sc consumed immediately (one sc live at a time)
        {
            const f32x16_t sc = __builtin_amdgcn_mfma_f32_32x32x16_bf16(A.v, Bs0.v, bc, 0, 0, 0);
            UBv PA;
            PA.u[0] = pks(sc[0],  sc[1]);
            PA.u[1] = pks(sc[2],  sc[3]);
            PA.u[2] = pks(sc[4],  sc[5]);
            PA.u[3] = pks(sc[6],  sc[7]);
            pvC0 = __builtin_amdgcn_mfma_f32_32x32x16_bf16(PA.v, B0.v, pvC0, 0, 0, 0);
            UBv PB;
            PB.u[0] = pks(sc[8],  sc[9]);
            PB.u[1] = pks(sc[10], sc[11]);
            PB.u[2] = pks(sc[12], sc[13]);
            PB.u[3] = pks(sc[14], sc[15]);
            pvC0 = __builtin_amdgcn_mfma_f32_32x32x16_bf16(PB.v, B1.v, pvC0, 0, 0, 0);
        }
        // head1
        {
            const f32x16_t sc = __builtin_amdgcn_mfma_f32_32x32x16_bf16(A.v, Bs1.v, bc, 0, 0, 0);
            UBv PA;
            PA.u[0] = pks(sc[0],  sc[1]);
            PA.u[1] = pks(sc[2],  sc[3]);
            PA.u[2] = pks(sc[4],  sc[5]);
            PA.u[3] = pks(sc[6],  sc[7]);
            pvC1 = __builtin_amdgcn_mfma_f32_32x32x16_bf16(PA.v, B0.v, pvC1, 0, 0, 0);
            UBv PB;
            PB.u[0] = pks(sc[8],  sc[9]);
            PB.u[1] = pks(sc[10], sc[11]);
            PB.u[2] = pks(sc[12], sc[13]);
            PB.u[3] = pks(sc[14], sc[15]);
            pvC1 = __builtin_amdgcn_mfma_f32_32x32x16_bf16(PB.v, B1.v, pvC1, 0, 0, 0);
        }
    }

    // ---- merge 4 k-splits + epilogue (both heads) ----
    const int d31 = lane & 31;
    if (d31 < 4) {
        const int slot = ((lane >> 5) << 2) | d31;
#pragma unroll
        for (int i = 0; i < 4; ++i) {
            float4 w0; w0.x = pvC0[i*4+0]; w0.y = pvC0[i*4+1]; w0.z = pvC0[i*4+2]; w0.w = pvC0[i*4+3];
            *(float4*)&RED[0][wid][slot][i * 4] = w0;
            float4 w1; w1.x = pvC1[i*4+0]; w1.y = pvC1[i*4+1]; w1.z = pvC1[i*4+2]; w1.w = pvC1[i*4+3];
            *(float4*)&RED[1][wid][slot][i * 4] = w1;
        }
    }
    __syncthreads();

    if (wid < 2 && lane < 32) {
        const int head = wid;
        const int hh   = head ? h1 : h0;
        const float* wvp = Wv + hh * 9;   // wave-uniform scalar loads
        const int qrow = lane;
        const int hh2 = (qrow >> 2) & 1;
        const int r   = (qrow & 3) | ((qrow >> 3) << 2);
        float acc[4];
#pragma unroll
        for (int d = 0; d < 4; ++d)
            acc[d] = (RED[head][0][hh2 * 4 + d][r] + RED[head][1][hh2 * 4 + d][r])
                   + (RED[head][2][hh2 * 4 + d][r] + RED[head][3][hh2 * 4 + d][r]);
        const float inv = 1.0f / fmaxf(acc[3], 1e-37f);
        const float r0 = acc[0] * inv, r1 = acc[1] * inv, r2 = acc[2] * inv;
        const float o0 = r0 * wvp[0] + r1 * wvp[3] + r2 * wvp[6];
        const float o1 = r0 * wvp[1] + r1 * wvp[4] + r2 * wvp[7];
        const float o2 = r0 * wvp[2] + r1 * wvp[5] + r2 * wvp[8];
        const int bhO = b * NH + hh;
        const int o   = bhO * (SEQ * 3) + (qb * 32 + qrow) * 3;
        const int second = NB * NH * SEQ * 3;
        out[o + 0] = o0; out[o + 1] = o1; out[o + 2] = o2;
        out[o + second + 0] = o0; out[o + second + 1] = o1; out[o + second + 2] = o2;
    }
}

extern "C" void kernel_launch(void* const* d_in, const int* in_sizes, int n_in,
                              void* d_out, int out_size, void* d_ws, size_t ws_size,
                              hipStream_t stream) {
    const float* x  = (const float*)d_in[0];
    const float* Wq = (const float*)d_in[1];
    const float* Wk = (const float*)d_in[2];
    const float* Wv = (const float*)d_in[3];
    float* out = (float*)d_out;
    (void)in_sizes; (void)n_in; (void)d_ws; (void)ws_size; (void)out_size;

    const int grid = NB * (NH / 2) * (SEQ / 32);  // 1024 blocks, 2 heads each
    attn_mfma<<<grid, 256, 0, stream>>>(x, Wq, Wk, Wv, out);
}

// Round 19
// 17.884 us; speedup vs baseline: 1.4608x; 1.0462x over previous
//
#include <hip/hip_runtime.h>

#define SEQ 2048
#define NH 8
#define NB 4

typedef unsigned int u32;
typedef short bf16x8_t __attribute__((ext_vector_type(8)));
typedef float f32x16_t __attribute__((ext_vector_type(16)));

// pack 2 f32 -> 2 bf16, round-half-up (proven R7-R18) - staging only
__device__ __forceinline__ u32 pkb(float a, float b) {
    const u32 ua = __builtin_bit_cast(u32, a) + 0x8000u;
    const u32 ub = __builtin_bit_cast(u32, b) + 0x8000u;
    return __builtin_amdgcn_perm(ub, ua, 0x07060302u);  // {a.bf16, b.bf16}
}
// sc = s*2^7 + 16256 + 2^23 (bias in MFMA C; f32 in [2^23,2^24) -> mantissa IS the
// integer). bits(sc).lo16 == bf16(2^s). P-pair = ONE v_perm, zero cvt. (proven R18)
__device__ __forceinline__ u32 pks(float Fa, float Fb) {
    return __builtin_amdgcn_perm(__builtin_bit_cast(u32, Fb),
                                 __builtin_bit_cast(u32, Fa), 0x05040100u);
}

union UBv { bf16x8_t v; u32 u[4]; };

__global__ __launch_bounds__(256)   // NOTE: never add min-waves (R4/R5/R14 NaN)
void attn_mfma(const float* __restrict__ x, const float* __restrict__ Wq,
               const float* __restrict__ Wk, const float* __restrict__ Wv,
               float* __restrict__ out) {
    // VT4: [kt=128][d=4][pos=16] bf16; rows d={x0,x1,x2,ones}; key m at pos pi(m)
    //      (pi = bit2<->bit3 swap). Serves PV-B (2x b128 broadcast reads). 16 KB
    // RED: [head4][wid][slot][16] cross-wave partials (4 heads)           8 KB
    __shared__ __align__(16) char VT4[128 * 128];
    __shared__ __align__(16) float RED[4][4][8][16];

    const int tid = threadIdx.x;
    const int blk = blockIdx.x;
    const int qb   = blk & 63;     // 32-query tile
    const int rest = blk >> 6;
    const int hp   = rest & 1;     // head-quad (0: h0-3, 1: h4-7)
    const int b    = rest >> 1;
    const int hbase = hp * 4;

    const float* xb = x + b * SEQ * 3;

    const int lane = tid & 63;
    const int wid  = tid >> 6;    // k-split: 512 keys per wave
    const int ql   = lane & 31;
    const int q    = qb * 32 + ql;
    const int kbase = wid * 512;

    // ---- A-fragments -> registers (amortized over 4 heads now) ----
    float ax0[16], ax1[16], ax2[16];
#pragma unroll
    for (int t = 0; t < 16; ++t) {
        const float* kp = xb + (kbase + t * 32 + ql) * 3;
        ax0[t] = kp[0]; ax1[t] = kp[1]; ax2[t] = kp[2];
    }

    // ---- staging: 8 keys per thread into VT4, pi-permuted positions ----
    {
        const float4* xg = (const float4*)xb;
        float xv[24];
        const float4 t0 = xg[tid * 6 + 0]; xv[0]=t0.x; xv[1]=t0.y; xv[2]=t0.z; xv[3]=t0.w;
        const float4 t1 = xg[tid * 6 + 1]; xv[4]=t1.x; xv[5]=t1.y; xv[6]=t1.z; xv[7]=t1.w;
        const float4 t2 = xg[tid * 6 + 2]; xv[8]=t2.x; xv[9]=t2.y; xv[10]=t2.z; xv[11]=t2.w;
        const float4 t3 = xg[tid * 6 + 3]; xv[12]=t3.x; xv[13]=t3.y; xv[14]=t3.z; xv[15]=t3.w;
        const float4 t4 = xg[tid * 6 + 4]; xv[16]=t4.x; xv[17]=t4.y; xv[18]=t4.z; xv[19]=t4.w;
        const float4 t5 = xg[tid * 6 + 5]; xv[20]=t5.x; xv[21]=t5.y; xv[22]=t5.z; xv[23]=t5.w;
        const int kt   = tid >> 1;
        const int half = tid & 1;
        const int slotA = half * 4;
        char* base = VT4 + kt * 128;
#pragma unroll
        for (int d = 0; d < 3; ++d) {
            uint2 wa, wb;
            wa.x = pkb(xv[0 + d],  xv[3 + d]);
            wa.y = pkb(xv[6 + d],  xv[9 + d]);
            wb.x = pkb(xv[12 + d], xv[15 + d]);
            wb.y = pkb(xv[18 + d], xv[21 + d]);
            *(uint2*)(base + d * 32 + slotA * 2)      = wa;
            *(uint2*)(base + d * 32 + slotA * 2 + 16) = wb;
        }
        uint4 ones; ones.x = ones.y = ones.z = ones.w = 0x3F803F80u;
        *(uint4*)(base + 96 + half * 16) = ones;
    }

    // pack A-frag registers: A0 full, A1 halves packed 2-tiles-per-reg
    u32 A0[16], A1h[8];
#pragma unroll
    for (int t = 0; t < 16; ++t) A0[t] = pkb(ax0[t], ax1[t]);
#pragma unroll
    for (int j = 0; j < 8; ++j)  A1h[j] = pkb(ax2[2 * j], ax2[2 * j + 1]);

    // u-vectors for FOUR heads, PRE-SCALED by 2^7 (mantissa-trick, proven R18)
    const float* gq = xb + q * 3;
    const float xq0 = gq[0], xq1 = gq[1], xq2 = gq[2];
    const float cc = 0.5773502691896258f * 1.4426950408889634f * 128.0f;
    float uu[4][3];
#pragma unroll
    for (int hh = 0; hh < 4; ++hh) {
        const float* wqp = Wq + (hbase + hh) * 9;
        const float* wkp = Wk + (hbase + hh) * 9;
        const float Q0 = xq0 * wqp[0] + xq1 * wqp[3] + xq2 * wqp[6];
        const float Q1 = xq0 * wqp[1] + xq1 * wqp[4] + xq2 * wqp[7];
        const float Q2 = xq0 * wqp[2] + xq1 * wqp[5] + xq2 * wqp[8];
        uu[hh][0] = (Q0 * wkp[0] + Q1 * wkp[1] + Q2 * wkp[2]) * cc;
        uu[hh][1] = (Q0 * wkp[3] + Q1 * wkp[4] + Q2 * wkp[5]) * cc;
        uu[hh][2] = (Q0 * wkp[6] + Q1 * wkp[7] + Q2 * wkp[8]) * cc;
    }

    __syncthreads();

    // scores-mfma B operands for 4 heads (k rows >= 4 zero; lanes>=32 all zero)
    u32 BsW[4][2];
#pragma unroll
    for (int hh = 0; hh < 4; ++hh) {
        BsW[hh][0] = (lane < 32) ? pkb(uu[hh][0], uu[hh][1]) : 0u;
        BsW[hh][1] = (lane < 32) ? pkb(uu[hh][2], 0.f) : 0u;
    }

    // PV-B address (proven R11-R18)
    const char* vb = VT4 + wid * 4096 + (lane & 3) * 32 + (lane >> 5) * 16;

    f32x16_t bc;                      // mantissa-trick bias as MFMA C-operand
#pragma unroll
    for (int i = 0; i < 16; ++i) bc[i] = 8404864.0f;   // 2^23 + 127*2^7

    const int d31 = lane & 31;
    const int slot = ((lane >> 5) << 2) | d31;

    // ---- TWO PASSES of the R18-proven loop: head-pair per pass, RED dump between ----
#pragma unroll
    for (int pass = 0; pass < 2; ++pass) {
        UBv Bs0, Bs1;
        Bs0.u[0] = BsW[2 * pass + 0][0]; Bs0.u[1] = BsW[2 * pass + 0][1];
        Bs0.u[2] = 0u; Bs0.u[3] = 0u;
        Bs1.u[0] = BsW[2 * pass + 1][0]; Bs1.u[1] = BsW[2 * pass + 1][1];
        Bs1.u[2] = 0u; Bs1.u[3] = 0u;

        f32x16_t pvC0 = {};
        f32x16_t pvC1 = {};
#pragma unroll
        for (int t = 0; t < 16; ++t) {
            const uint4 bv0 = *(const uint4*)(vb + t * 256);
            const uint4 bv1 = *(const uint4*)(vb + t * 256 + 128);
            UBv B0; B0.u[0] = bv0.x; B0.u[1] = bv0.y; B0.u[2] = bv0.z; B0.u[3] = bv0.w;
            UBv B1; B1.u[0] = bv1.x; B1.u[1] = bv1.y; B1.u[2] = bv1.z; B1.u[3] = bv1.w;

            UBv A;
            A.u[0] = A0[t];
            A.u[1] = (t & 1) ? (A1h[t >> 1] >> 16) : (A1h[t >> 1] & 0xFFFFu);
            A.u[2] = 0u; A.u[3] = 0u;

            {
                const f32x16_t sc = __builtin_amdgcn_mfma_f32_32x32x16_bf16(A.v, Bs0.v, bc, 0, 0, 0);
                UBv PA;
                PA.u[0] = pks(sc[0],  sc[1]);
                PA.u[1] = pks(sc[2],  sc[3]);
                PA.u[2] = pks(sc[4],  sc[5]);
                PA.u[3] = pks(sc[6],  sc[7]);
                pvC0 = __builtin_amdgcn_mfma_f32_32x32x16_bf16(PA.v, B0.v, pvC0, 0, 0, 0);
                UBv PB;
                PB.u[0] = pks(sc[8],  sc[9]);
                PB.u[1] = pks(sc[10], sc[11]);
                PB.u[2] = pks(sc[12], sc[13]);
                PB.u[3] = pks(sc[14], sc[15]);
                pvC0 = __builtin_amdgcn_mfma_f32_32x32x16_bf16(PB.v, B1.v, pvC0, 0, 0, 0);
            }
            {
                const f32x16_t sc = __builtin_amdgcn_mfma_f32_32x32x16_bf16(A.v, Bs1.v, bc, 0, 0, 0);
                UBv PA;
                PA.u[0] = pks(sc[0],  sc[1]);
                PA.u[1] = pks(sc[2],  sc[3]);
                PA.u[2] = pks(sc[4],  sc[5]);
                PA.u[3] = pks(sc[6],  sc[7]);
                pvC1 = __builtin_amdgcn_mfma_f32_32x32x16_bf16(PA.v, B0.v, pvC1, 0, 0, 0);
                UBv PB;
                PB.u[0] = pks(sc[8],  sc[9]);
                PB.u[1] = pks(sc[10], sc[11]);
                PB.u[2] = pks(sc[12], sc[13]);
                PB.u[3] = pks(sc[14], sc[15]);
                pvC1 = __builtin_amdgcn_mfma_f32_32x32x16_bf16(PB.v, B1.v, pvC1, 0, 0, 0);
            }
        }
        // dump this pass's partials (kills pvC liveness before next pass)
        if (d31 < 4) {
#pragma unroll
            for (int i = 0; i < 4; ++i) {
                float4 w0; w0.x = pvC0[i*4+0]; w0.y = pvC0[i*4+1];
                w0.z = pvC0[i*4+2]; w0.w = pvC0[i*4+3];
                *(float4*)&RED[2 * pass + 0][wid][slot][i * 4] = w0;
                float4 w1; w1.x = pvC1[i*4+0]; w1.y = pvC1[i*4+1];
                w1.z = pvC1[i*4+2]; w1.w = pvC1[i*4+3];
                *(float4*)&RED[2 * pass + 1][wid][slot][i * 4] = w1;
            }
        }
    }
    __syncthreads();

    // ---- merge 4 k-splits + epilogue: wave wid handles head hbase+wid ----
    if (lane < 32) {
        const int head = wid;
        const int hh   = hbase + head;
        const float* wvp = Wv + hh * 9;   // wave-uniform scalar loads
        const int qrow = lane;
        const int hh2 = (qrow >> 2) & 1;
        const int r   = (qrow & 3) | ((qrow >> 3) << 2);
        float acc[4];
#pragma unroll
        for (int d = 0; d < 4; ++d)
            acc[d] = (RED[head][0][hh2 * 4 + d][r] + RED[head][1][hh2 * 4 + d][r])
                   + (RED[head][2][hh2 * 4 + d][r] + RED[head][3][hh2 * 4 + d][r]);
        const float inv = 1.0f / fmaxf(acc[3], 1e-37f);
        const float r0 = acc[0] * inv, r1 = acc[1] * inv, r2 = acc[2] * inv;
        const float o0 = r0 * wvp[0] + r1 * wvp[3] + r2 * wvp[6];
        const float o1 = r0 * wvp[1] + r1 * wvp[4] + r2 * wvp[7];
        const float o2 = r0 * wvp[2] + r1 * wvp[5] + r2 * wvp[8];
        const int bhO = b * NH + hh;
        const int o   = bhO * (SEQ * 3) + (qb * 32 + qrow) * 3;
        const int second = NB * NH * SEQ * 3;
        out[o + 0] = o0; out[o + 1] = o1; out[o + 2] = o2;
        out[o + second + 0] = o0; out[o + second + 1] = o1; out[o + second + 2] = o2;
    }
}

extern "C" void kernel_launch(void* const* d_in, const int* in_sizes, int n_in,
                              void* d_out, int out_size, void* d_ws, size_t ws_size,
                              hipStream_t stream) {
    const float* x  = (const float*)d_in[0];
    const float* Wq = (const float*)d_in[1];
    const float* Wk = (const float*)d_in[2];
    const float* Wv = (const float*)d_in[3];
    float* out = (float*)d_out;
    (void)in_sizes; (void)n_in; (void)d_ws; (void)ws_size; (void)out_size;

    const int grid = NB * (NH / 4) * (SEQ / 32);  // 512 blocks, 4 heads each
    attn_mfma<<<grid, 256, 0, stream>>>(x, Wq, Wk, Wv, out);
}

// Round 20
// 17.084 us; speedup vs baseline: 1.5292x; 1.0468x over previous
//
#include <hip/hip_runtime.h>

#define SEQ 2048
#define NH 8
#define NB 4

typedef unsigned int u32;
typedef short bf16x8_t __attribute__((ext_vector_type(8)));
typedef float f32x16_t __attribute__((ext_vector_type(16)));

// pack 2 f32 -> 2 bf16, round-half-up (proven R7-R19) - staging only
__device__ __forceinline__ u32 pkb(float a, float b) {
    const u32 ua = __builtin_bit_cast(u32, a) + 0x8000u;
    const u32 ub = __builtin_bit_cast(u32, b) + 0x8000u;
    return __builtin_amdgcn_perm(ub, ua, 0x07060302u);  // {a.bf16, b.bf16}
}
// sc = s*2^7 + 16256 + 2^23 (bias in MFMA C; mantissa IS the integer).
// bits(sc).lo16 == bf16(2^s). P-pair = ONE v_perm, zero cvt. (proven R18/R19)
__device__ __forceinline__ u32 pks(float Fa, float Fb) {
    return __builtin_amdgcn_perm(__builtin_bit_cast(u32, Fb),
                                 __builtin_bit_cast(u32, Fa), 0x05040100u);
}

union UBv { bf16x8_t v; u32 u[4]; };

__global__ __launch_bounds__(512)   // NOTE: never add min-waves (R4/R5/R14 NaN)
void attn_mfma(const float* __restrict__ x, const float* __restrict__ Wq,
               const float* __restrict__ Wk, const float* __restrict__ Wv,
               float* __restrict__ out) {
    // VT4: [kt=128][d=4][pos=16] bf16; rows d={x0,x1,x2,ones}; key m at pos pi(m)
    //      (pi = bit2<->bit3 swap). Serves PV-B (2x b128 broadcast reads). 16 KB
    // RED: [head4][wid8][slot][16] cross-wave partials                     16 KB
    __shared__ __align__(16) char VT4[128 * 128];
    __shared__ __align__(16) float RED[4][8][8][16];

    const int tid = threadIdx.x;
    const int blk = blockIdx.x;
    const int qb   = blk & 63;     // 32-query tile
    const int rest = blk >> 6;
    const int hp   = rest & 1;     // head-quad (0: h0-3, 1: h4-7)
    const int b    = rest >> 1;
    const int hbase = hp * 4;

    const float* xb = x + b * SEQ * 3;

    const int lane = tid & 63;
    const int wid  = tid >> 6;    // 8 waves: k-split 8-way, 256 keys per wave
    const int ql   = lane & 31;
    const int q    = qb * 32 + ql;
    const int kbase = wid * 256;

    // ---- A-fragments -> registers: lane's own key, 8 tiles per wave ----
    float ax0[8], ax1[8], ax2[8];
#pragma unroll
    for (int t = 0; t < 8; ++t) {
        const float* kp = xb + (kbase + t * 32 + ql) * 3;
        ax0[t] = kp[0]; ax1[t] = kp[1]; ax2[t] = kp[2];
    }

    // ---- staging: 4 keys per thread into VT4, pi-permuted positions ----
    {
        const float4* xg = (const float4*)xb;
        float xv[12];
        const float4 t0 = xg[tid * 3 + 0]; xv[0]=t0.x; xv[1]=t0.y; xv[2]=t0.z; xv[3]=t0.w;
        const float4 t1 = xg[tid * 3 + 1]; xv[4]=t1.x; xv[5]=t1.y; xv[6]=t1.z; xv[7]=t1.w;
        const float4 t2 = xg[tid * 3 + 2]; xv[8]=t2.x; xv[9]=t2.y; xv[10]=t2.z; xv[11]=t2.w;
        const int k0   = tid * 4;
        const int kt   = k0 >> 4;               // 16-key tile
        const int run  = k0 & 12;               // 4-key run within tile: 0,4,8,12
        const int slotA = (run & 3) | ((run & 4) << 1) | ((run & 8) >> 1);  // pi(run)
        char* base = VT4 + kt * 128;
#pragma unroll
        for (int d = 0; d < 3; ++d) {
            uint2 wa;
            wa.x = pkb(xv[0 + d], xv[3 + d]);
            wa.y = pkb(xv[6 + d], xv[9 + d]);
            *(uint2*)(base + d * 32 + slotA * 2) = wa;
        }
        uint2 ones; ones.x = ones.y = 0x3F803F80u;
        *(uint2*)(base + 96 + (k0 & 15) * 2) = ones;
    }

    // pack A-frag registers: A0 full, A1 halves packed 2-tiles-per-reg
    u32 A0[8], A1h[4];
#pragma unroll
    for (int t = 0; t < 8; ++t) A0[t] = pkb(ax0[t], ax1[t]);
#pragma unroll
    for (int j = 0; j < 4; ++j) A1h[j] = pkb(ax2[2 * j], ax2[2 * j + 1]);

    // u-vectors for FOUR heads, PRE-SCALED by 2^7 (mantissa trick, proven R18/R19)
    const float* gq = xb + q * 3;
    const float xq0 = gq[0], xq1 = gq[1], xq2 = gq[2];
    const float cc = 0.5773502691896258f * 1.4426950408889634f * 128.0f;
    float uu[4][3];
#pragma unroll
    for (int hh = 0; hh < 4; ++hh) {
        const float* wqp = Wq + (hbase + hh) * 9;
        const float* wkp = Wk + (hbase + hh) * 9;
        const float Q0 = xq0 * wqp[0] + xq1 * wqp[3] + xq2 * wqp[6];
        const float Q1 = xq0 * wqp[1] + xq1 * wqp[4] + xq2 * wqp[7];
        const float Q2 = xq0 * wqp[2] + xq1 * wqp[5] + xq2 * wqp[8];
        uu[hh][0] = (Q0 * wkp[0] + Q1 * wkp[1] + Q2 * wkp[2]) * cc;
        uu[hh][1] = (Q0 * wkp[3] + Q1 * wkp[4] + Q2 * wkp[5]) * cc;
        uu[hh][2] = (Q0 * wkp[6] + Q1 * wkp[7] + Q2 * wkp[8]) * cc;
    }

    __syncthreads();

    // scores-mfma B operand words for 4 heads
    u32 BsW[4][2];
#pragma unroll
    for (int hh = 0; hh < 4; ++hh) {
        BsW[hh][0] = (lane < 32) ? pkb(uu[hh][0], uu[hh][1]) : 0u;
        BsW[hh][1] = (lane < 32) ? pkb(uu[hh][2], 0.f) : 0u;
    }

    // PV-B address: wave's 8 tiles start at kt = wid*16 (256B per 16-key tile... 2048B per wave)
    const char* vb = VT4 + wid * 2048 + (lane & 3) * 32 + (lane >> 5) * 16;

    f32x16_t bc;                      // mantissa-trick bias as MFMA C-operand
#pragma unroll
    for (int i = 0; i < 16; ++i) bc[i] = 8404864.0f;   // 2^23 + 127*2^7

    const int d31 = lane & 31;
    const int slot = ((lane >> 5) << 2) | d31;

    // ---- TWO PASSES: head-pair per pass, 8 tiles, RED dump between ----
#pragma unroll
    for (int pass = 0; pass < 2; ++pass) {
        UBv Bs0, Bs1;
        Bs0.u[0] = BsW[2 * pass + 0][0]; Bs0.u[1] = BsW[2 * pass + 0][1];
        Bs0.u[2] = 0u; Bs0.u[3] = 0u;
        Bs1.u[0] = BsW[2 * pass + 1][0]; Bs1.u[1] = BsW[2 * pass + 1][1];
        Bs1.u[2] = 0u; Bs1.u[3] = 0u;

        f32x16_t pvC0 = {};
        f32x16_t pvC1 = {};
#pragma unroll
        for (int t = 0; t < 8; ++t) {
            const uint4 bv0 = *(const uint4*)(vb + t * 256);
            const uint4 bv1 = *(const uint4*)(vb + t * 256 + 128);
            UBv B0; B0.u[0] = bv0.x; B0.u[1] = bv0.y; B0.u[2] = bv0.z; B0.u[3] = bv0.w;
            UBv B1; B1.u[0] = bv1.x; B1.u[1] = bv1.y; B1.u[2] = bv1.z; B1.u[3] = bv1.w;

            UBv A;
            A.u[0] = A0[t];
            A.u[1] = (t & 1) ? (A1h[t >> 1] >> 16) : (A1h[t >> 1] & 0xFFFFu);
            A.u[2] = 0u; A.u[3] = 0u;

            {
                const f32x16_t sc = __builtin_amdgcn_mfma_f32_32x32x16_bf16(A.v, Bs0.v, bc, 0, 0, 0);
                UBv PA;
                PA.u[0] = pks(sc[0],  sc[1]);
                PA.u[1] = pks(sc[2],  sc[3]);
                PA.u[2] = pks(sc[4],  sc[5]);
                PA.u[3] = pks(sc[6],  sc[7]);
                pvC0 = __builtin_amdgcn_mfma_f32_32x32x16_bf16(PA.v, B0.v, pvC0, 0, 0, 0);
                UBv PB;
                PB.u[0] = pks(sc[8],  sc[9]);
                PB.u[1] = pks(sc[10], sc[11]);
                PB.u[2] = pks(sc[12], sc[13]);
                PB.u[3] = pks(sc[14], sc[15]);
                pvC0 = __builtin_amdgcn_mfma_f32_32x32x16_bf16(PB.v, B1.v, pvC0, 0, 0, 0);
            }
            {
                const f32x16_t sc = __builtin_amdgcn_mfma_f32_32x32x16_bf16(A.v, Bs1.v, bc, 0, 0, 0);
                UBv PA;
                PA.u[0] = pks(sc[0],  sc[1]);
                PA.u[1] = pks(sc[2],  sc[3]);
                PA.u[2] = pks(sc[4],  sc[5]);
                PA.u[3] = pks(sc[6],  sc[7]);
                pvC1 = __builtin_amdgcn_mfma_f32_32x32x16_bf16(PA.v, B0.v, pvC1, 0, 0, 0);
                UBv PB;
                PB.u[0] = pks(sc[8],  sc[9]);
                PB.u[1] = pks(sc[10], sc[11]);
                PB.u[2] = pks(sc[12], sc[13]);
                PB.u[3] = pks(sc[14], sc[15]);
                pvC1 = __builtin_amdgcn_mfma_f32_32x32x16_bf16(PB.v, B1.v, pvC1, 0, 0, 0);
            }
        }
        // dump this pass's partials (kills pvC liveness before next pass)
        if (d31 < 4) {
#pragma unroll
            for (int i = 0; i < 4; ++i) {
                float4 w0; w0.x = pvC0[i*4+0]; w0.y = pvC0[i*4+1];
                w0.z = pvC0[i*4+2]; w0.w = pvC0[i*4+3];
                *(float4*)&RED[2 * pass + 0][wid][slot][i * 4] = w0;
                float4 w1; w1.x = pvC1[i*4+0]; w1.y = pvC1[i*4+1];
                w1.z = pvC1[i*4+2]; w1.w = pvC1[i*4+3];
                *(float4*)&RED[2 * pass + 1][wid][slot][i * 4] = w1;
            }
        }
    }
    __syncthreads();

    // ---- merge 8 k-splits + epilogue: waves 0-3 handle head hbase+wid ----
    if (wid < 4 && lane < 32) {
        const int head = wid;
        const int hh   = hbase + head;
        const float* wvp = Wv + hh * 9;   // wave-uniform scalar loads
        const int qrow = lane;
        const int hh2 = (qrow >> 2) & 1;
        const int r   = (qrow & 3) | ((qrow >> 3) << 2);
        float acc[4];
#pragma unroll
        for (int d = 0; d < 4; ++d) {
            float s = 0.f;
#pragma unroll
            for (int w = 0; w < 8; ++w) s += RED[head][w][hh2 * 4 + d][r];
            acc[d] = s;
        }
        const float inv = 1.0f / fmaxf(acc[3], 1e-37f);
        const float r0 = acc[0] * inv, r1 = acc[1] * inv, r2 = acc[2] * inv;
        const float o0 = r0 * wvp[0] + r1 * wvp[3] + r2 * wvp[6];
        const float o1 = r0 * wvp[1] + r1 * wvp[4] + r2 * wvp[7];
        const float o2 = r0 * wvp[2] + r1 * wvp[5] + r2 * wvp[8];
        const int bhO = b * NH + hh;
        const int o   = bhO * (SEQ * 3) + (qb * 32 + qrow) * 3;
        const int second = NB * NH * SEQ * 3;
        out[o + 0] = o0; out[o + 1] = o1; out[o + 2] = o2;
        out[o + second + 0] = o0; out[o + second + 1] = o1; out[o + second + 2] = o2;
    }
}

extern "C" void kernel_launch(void* const* d_in, const int* in_sizes, int n_in,
                              void* d_out, int out_size, void* d_ws, size_t ws_size,
                              hipStream_t stream) {
    const float* x  = (const float*)d_in[0];
    const float* Wq = (const float*)d_in[1];
    const float* Wk = (const float*)d_in[2];
    const float* Wv = (const float*)d_in[3];
    float* out = (float*)d_out;
    (void)in_sizes; (void)n_in; (void)d_ws; (void)ws_size; (void)out_size;

    const int grid = NB * (NH / 4) * (SEQ / 32);  // 512 blocks x 512 threads
    attn_mfma<<<grid, 512, 0, stream>>>(x, Wq, Wk, Wv, out);
}

// Round 21
// 16.831 us; speedup vs baseline: 1.5522x; 1.0150x over previous
//
#include <hip/hip_runtime.h>

#define SEQ 2048
#define NH 8
#define NB 4

typedef unsigned int u32;
typedef short bf16x8_t __attribute__((ext_vector_type(8)));
typedef float f32x16_t __attribute__((ext_vector_type(16)));

// pack 2 f32 -> 2 bf16, round-half-up (proven R7-R20) - staging only
__device__ __forceinline__ u32 pkb(float a, float b) {
    const u32 ua = __builtin_bit_cast(u32, a) + 0x8000u;
    const u32 ub = __builtin_bit_cast(u32, b) + 0x8000u;
    return __builtin_amdgcn_perm(ub, ua, 0x07060302u);  // {a.bf16, b.bf16}
}
// sc = s*2^7 + 16256 + 2^23 (bias in MFMA C; mantissa IS the integer).
// bits(sc).lo16 == bf16(2^s). P-pair = ONE v_perm, zero cvt. (proven R18-R20)
__device__ __forceinline__ u32 pks(float Fa, float Fb) {
    return __builtin_amdgcn_perm(__builtin_bit_cast(u32, Fb),
                                 __builtin_bit_cast(u32, Fa), 0x05040100u);
}

union UBv { bf16x8_t v; u32 u[4]; };

__global__ __launch_bounds__(512)   // NOTE: never add min-waves (R4/R5/R14 NaN)
void attn_mfma(const float* __restrict__ x, const float* __restrict__ Wq,
               const float* __restrict__ Wk, const float* __restrict__ Wv,
               float* __restrict__ out) {
    // VT4: [kt=128][d=4][pos=16] bf16; rows d={x0,x1,x2,ones}; key m at pos pi(m)
    //      (pi = bit2<->bit3 swap). Serves PV-B (2x b128 broadcast reads). 16 KB
    // RED: [head4][wid8][slot][16] cross-wave partials                     16 KB
    __shared__ __align__(16) char VT4[128 * 128];
    __shared__ __align__(16) float RED[4][8][8][16];

    const int tid = threadIdx.x;
    const int blk = blockIdx.x;
    const int qb   = blk & 63;     // 32-query tile
    const int rest = blk >> 6;
    const int hp   = rest & 1;     // head-quad (0: h0-3, 1: h4-7)
    const int b    = rest >> 1;
    const int hbase = hp * 4;

    const float* xb = x + b * SEQ * 3;

    const int lane = tid & 63;
    const int wid  = tid >> 6;    // 8 waves: k-split 8-way, 256 keys per wave
    const int ql   = lane & 31;
    const int q    = qb * 32 + ql;
    const int kbase = wid * 256;

    // ---- A-fragments -> registers: lane's own key, 8 tiles per wave ----
    float ax0[8], ax1[8], ax2[8];
#pragma unroll
    for (int t = 0; t < 8; ++t) {
        const float* kp = xb + (kbase + t * 32 + ql) * 3;
        ax0[t] = kp[0]; ax1[t] = kp[1]; ax2[t] = kp[2];
    }

    // ---- staging: 4 keys per thread into VT4, pi-permuted positions ----
    {
        const float4* xg = (const float4*)xb;
        float xv[12];
        const float4 t0 = xg[tid * 3 + 0]; xv[0]=t0.x; xv[1]=t0.y; xv[2]=t0.z; xv[3]=t0.w;
        const float4 t1 = xg[tid * 3 + 1]; xv[4]=t1.x; xv[5]=t1.y; xv[6]=t1.z; xv[7]=t1.w;
        const float4 t2 = xg[tid * 3 + 2]; xv[8]=t2.x; xv[9]=t2.y; xv[10]=t2.z; xv[11]=t2.w;
        const int k0   = tid * 4;
        const int kt   = k0 >> 4;               // 16-key tile
        const int run  = k0 & 12;               // 4-key run within tile: 0,4,8,12
        const int slotA = (run & 3) | ((run & 4) << 1) | ((run & 8) >> 1);  // pi(run)
        char* base = VT4 + kt * 128;
#pragma unroll
        for (int d = 0; d < 3; ++d) {
            uint2 wa;
            wa.x = pkb(xv[0 + d], xv[3 + d]);
            wa.y = pkb(xv[6 + d], xv[9 + d]);
            *(uint2*)(base + d * 32 + slotA * 2) = wa;
        }
        uint2 ones; ones.x = ones.y = 0x3F803F80u;
        *(uint2*)(base + 96 + (k0 & 15) * 2) = ones;
    }

    // pack A-frag registers: A0 full, A1 halves packed 2-tiles-per-reg
    u32 A0[8], A1h[4];
#pragma unroll
    for (int t = 0; t < 8; ++t) A0[t] = pkb(ax0[t], ax1[t]);
#pragma unroll
    for (int j = 0; j < 4; ++j) A1h[j] = pkb(ax2[2 * j], ax2[2 * j + 1]);

    // u-vectors for FOUR heads, PRE-SCALED by 2^7 (mantissa trick, proven R18-R20)
    const float* gq = xb + q * 3;
    const float xq0 = gq[0], xq1 = gq[1], xq2 = gq[2];
    const float cc = 0.5773502691896258f * 1.4426950408889634f * 128.0f;
    float uu[4][3];
#pragma unroll
    for (int hh = 0; hh < 4; ++hh) {
        const float* wqp = Wq + (hbase + hh) * 9;
        const float* wkp = Wk + (hbase + hh) * 9;
        const float Q0 = xq0 * wqp[0] + xq1 * wqp[3] + xq2 * wqp[6];
        const float Q1 = xq0 * wqp[1] + xq1 * wqp[4] + xq2 * wqp[7];
        const float Q2 = xq0 * wqp[2] + xq1 * wqp[5] + xq2 * wqp[8];
        uu[hh][0] = (Q0 * wkp[0] + Q1 * wkp[1] + Q2 * wkp[2]) * cc;
        uu[hh][1] = (Q0 * wkp[3] + Q1 * wkp[4] + Q2 * wkp[5]) * cc;
        uu[hh][2] = (Q0 * wkp[6] + Q1 * wkp[7] + Q2 * wkp[8]) * cc;
    }

    __syncthreads();

    // scores-mfma B operands for 4 heads
    UBv Bs0, Bs1, Bs2, Bs3;
    Bs0.u[0] = (lane < 32) ? pkb(uu[0][0], uu[0][1]) : 0u;
    Bs0.u[1] = (lane < 32) ? pkb(uu[0][2], 0.f) : 0u;
    Bs0.u[2] = 0u; Bs0.u[3] = 0u;
    Bs1.u[0] = (lane < 32) ? pkb(uu[1][0], uu[1][1]) : 0u;
    Bs1.u[1] = (lane < 32) ? pkb(uu[1][2], 0.f) : 0u;
    Bs1.u[2] = 0u; Bs1.u[3] = 0u;
    Bs2.u[0] = (lane < 32) ? pkb(uu[2][0], uu[2][1]) : 0u;
    Bs2.u[1] = (lane < 32) ? pkb(uu[2][2], 0.f) : 0u;
    Bs2.u[2] = 0u; Bs2.u[3] = 0u;
    Bs3.u[0] = (lane < 32) ? pkb(uu[3][0], uu[3][1]) : 0u;
    Bs3.u[1] = (lane < 32) ? pkb(uu[3][2], 0.f) : 0u;
    Bs3.u[2] = 0u; Bs3.u[3] = 0u;

    // PV-B address: wave's 8 tiles start at kt = wid*16 (2048 B per wave)
    const char* vb = VT4 + wid * 2048 + (lane & 3) * 32 + (lane >> 5) * 16;

    f32x16_t bc;                      // mantissa-trick bias as MFMA C-operand
#pragma unroll
    for (int i = 0; i < 16; ++i) bc[i] = 8404864.0f;   // 2^23 + 127*2^7

    const int d31 = lane & 31;
    const int slot = ((lane >> 5) << 2) | d31;

    f32x16_t pv0 = {}, pv1 = {}, pv2 = {}, pv3 = {};

    // ---- SINGLE PASS, tile-outer / head-inner: V b128 reads shared by 4 heads ----
#pragma unroll
    for (int t = 0; t < 8; ++t) {
        const uint4 bv0 = *(const uint4*)(vb + t * 256);
        const uint4 bv1 = *(const uint4*)(vb + t * 256 + 128);
        UBv B0; B0.u[0] = bv0.x; B0.u[1] = bv0.y; B0.u[2] = bv0.z; B0.u[3] = bv0.w;
        UBv B1; B1.u[0] = bv1.x; B1.u[1] = bv1.y; B1.u[2] = bv1.z; B1.u[3] = bv1.w;

        UBv A;
        A.u[0] = A0[t];
        A.u[1] = (t & 1) ? (A1h[t >> 1] >> 16) : (A1h[t >> 1] & 0xFFFFu);
        A.u[2] = 0u; A.u[3] = 0u;

        {
            const f32x16_t sc = __builtin_amdgcn_mfma_f32_32x32x16_bf16(A.v, Bs0.v, bc, 0, 0, 0);
            UBv PA;
            PA.u[0] = pks(sc[0],  sc[1]);  PA.u[1] = pks(sc[2],  sc[3]);
            PA.u[2] = pks(sc[4],  sc[5]);  PA.u[3] = pks(sc[6],  sc[7]);
            pv0 = __builtin_amdgcn_mfma_f32_32x32x16_bf16(PA.v, B0.v, pv0, 0, 0, 0);
            UBv PB;
            PB.u[0] = pks(sc[8],  sc[9]);  PB.u[1] = pks(sc[10], sc[11]);
            PB.u[2] = pks(sc[12], sc[13]); PB.u[3] = pks(sc[14], sc[15]);
            pv0 = __builtin_amdgcn_mfma_f32_32x32x16_bf16(PB.v, B1.v, pv0, 0, 0, 0);
        }
        {
            const f32x16_t sc = __builtin_amdgcn_mfma_f32_32x32x16_bf16(A.v, Bs1.v, bc, 0, 0, 0);
            UBv PA;
            PA.u[0] = pks(sc[0],  sc[1]);  PA.u[1] = pks(sc[2],  sc[3]);
            PA.u[2] = pks(sc[4],  sc[5]);  PA.u[3] = pks(sc[6],  sc[7]);
            pv1 = __builtin_amdgcn_mfma_f32_32x32x16_bf16(PA.v, B0.v, pv1, 0, 0, 0);
            UBv PB;
            PB.u[0] = pks(sc[8],  sc[9]);  PB.u[1] = pks(sc[10], sc[11]);
            PB.u[2] = pks(sc[12], sc[13]); PB.u[3] = pks(sc[14], sc[15]);
            pv1 = __builtin_amdgcn_mfma_f32_32x32x16_bf16(PB.v, B1.v, pv1, 0, 0, 0);
        }
        {
            const f32x16_t sc = __builtin_amdgcn_mfma_f32_32x32x16_bf16(A.v, Bs2.v, bc, 0, 0, 0);
            UBv PA;
            PA.u[0] = pks(sc[0],  sc[1]);  PA.u[1] = pks(sc[2],  sc[3]);
            PA.u[2] = pks(sc[4],  sc[5]);  PA.u[3] = pks(sc[6],  sc[7]);
            pv2 = __builtin_amdgcn_mfma_f32_32x32x16_bf16(PA.v, B0.v, pv2, 0, 0, 0);
            UBv PB;
            PB.u[0] = pks(sc[8],  sc[9]);  PB.u[1] = pks(sc[10], sc[11]);
            PB.u[2] = pks(sc[12], sc[13]); PB.u[3] = pks(sc[14], sc[15]);
            pv2 = __builtin_amdgcn_mfma_f32_32x32x16_bf16(PB.v, B1.v, pv2, 0, 0, 0);
        }
        {
            const f32x16_t sc = __builtin_amdgcn_mfma_f32_32x32x16_bf16(A.v, Bs3.v, bc, 0, 0, 0);
            UBv PA;
            PA.u[0] = pks(sc[0],  sc[1]);  PA.u[1] = pks(sc[2],  sc[3]);
            PA.u[2] = pks(sc[4],  sc[5]);  PA.u[3] = pks(sc[6],  sc[7]);
            pv3 = __builtin_amdgcn_mfma_f32_32x32x16_bf16(PA.v, B0.v, pv3, 0, 0, 0);
            UBv PB;
            PB.u[0] = pks(sc[8],  sc[9]);  PB.u[1] = pks(sc[10], sc[11]);
            PB.u[2] = pks(sc[12], sc[13]); PB.u[3] = pks(sc[14], sc[15]);
            pv3 = __builtin_amdgcn_mfma_f32_32x32x16_bf16(PB.v, B1.v, pv3, 0, 0, 0);
        }
    }

    // ---- dump partials + merge 8 k-splits + epilogue ----
    if (d31 < 4) {
#pragma unroll
        for (int i = 0; i < 4; ++i) {
            float4 w;
            w.x = pv0[i*4+0]; w.y = pv0[i*4+1]; w.z = pv0[i*4+2]; w.w = pv0[i*4+3];
            *(float4*)&RED[0][wid][slot][i * 4] = w;
            w.x = pv1[i*4+0]; w.y = pv1[i*4+1]; w.z = pv1[i*4+2]; w.w = pv1[i*4+3];
            *(float4*)&RED[1][wid][slot][i * 4] = w;
            w.x = pv2[i*4+0]; w.y = pv2[i*4+1]; w.z = pv2[i*4+2]; w.w = pv2[i*4+3];
            *(float4*)&RED[2][wid][slot][i * 4] = w;
            w.x = pv3[i*4+0]; w.y = pv3[i*4+1]; w.z = pv3[i*4+2]; w.w = pv3[i*4+3];
            *(float4*)&RED[3][wid][slot][i * 4] = w;
        }
    }
    __syncthreads();

    if (wid < 4 && lane < 32) {
        const int head = wid;
        const int hh   = hbase + head;
        const float* wvp = Wv + hh * 9;   // wave-uniform scalar loads
        const int qrow = lane;
        const int hh2 = (qrow >> 2) & 1;
        const int r   = (qrow & 3) | ((qrow >> 3) << 2);
        float acc[4];
#pragma unroll
        for (int d = 0; d < 4; ++d) {
            float s = 0.f;
#pragma unroll
            for (int w = 0; w < 8; ++w) s += RED[head][w][hh2 * 4 + d][r];
            acc[d] = s;
        }
        const float inv = 1.0f / fmaxf(acc[3], 1e-37f);
        const float r0 = acc[0] * inv, r1 = acc[1] * inv, r2 = acc[2] * inv;
        const float o0 = r0 * wvp[0] + r1 * wvp[3] + r2 * wvp[6];
        const float o1 = r0 * wvp[1] + r1 * wvp[4] + r2 * wvp[7];
        const float o2 = r0 * wvp[2] + r1 * wvp[5] + r2 * wvp[8];
        const int bhO = b * NH + hh;
        const int o   = bhO * (SEQ * 3) + (qb * 32 + qrow) * 3;
        const int second = NB * NH * SEQ * 3;
        out[o + 0] = o0; out[o + 1] = o1; out[o + 2] = o2;
        out[o + second + 0] = o0; out[o + second + 1] = o1; out[o + second + 2] = o2;
    }
}

extern "C" void kernel_launch(void* const* d_in, const int* in_sizes, int n_in,
                              void* d_out, int out_size, void* d_ws, size_t ws_size,
                              hipStream_t stream) {
    const float* x  = (const float*)d_in[0];
    const float* Wq = (const float*)d_in[1];
    const float* Wk = (const float*)d_in[2];
    const float* Wv = (const float*)d_in[3];
    float* out = (float*)d_out;
    (void)in_sizes; (void)n_in; (void)d_ws; (void)ws_size; (void)out_size;

    const int grid = NB * (NH / 4) * (SEQ / 32);  // 512 blocks x 512 threads
    attn_mfma<<<grid, 512, 0, stream>>>(x, Wq, Wk, Wv, out);
}

// Round 22
// 16.529 us; speedup vs baseline: 1.5805x; 1.0183x over previous
//
#include <hip/hip_runtime.h>

#define SEQ 2048
#define NH 8
#define NB 4

typedef unsigned int u32;
typedef short bf16x8_t __attribute__((ext_vector_type(8)));
typedef float f32x16_t __attribute__((ext_vector_type(16)));

// pack 2 f32 -> 2 bf16, round-half-up (proven R7-R21) - staging only
__device__ __forceinline__ u32 pkb(float a, float b) {
    const u32 ua = __builtin_bit_cast(u32, a) + 0x8000u;
    const u32 ub = __builtin_bit_cast(u32, b) + 0x8000u;
    return __builtin_amdgcn_perm(ub, ua, 0x07060302u);  // {a.bf16, b.bf16}
}
// sc = s*2^7 + 16256 + 2^23 (bias in MFMA C; mantissa IS the integer).
// bits(sc).lo16 == bf16(2^s). P-pair = ONE v_perm, zero cvt. (proven R18-R21)
__device__ __forceinline__ u32 pks(float Fa, float Fb) {
    return __builtin_amdgcn_perm(__builtin_bit_cast(u32, Fb),
                                 __builtin_bit_cast(u32, Fa), 0x05040100u);
}

union UBv { bf16x8_t v; u32 u[4]; };

__global__ __launch_bounds__(512)   // NOTE: never add min-waves (R4/R5/R14 NaN)
void attn_mfma(const float* __restrict__ x, const float* __restrict__ Wq,
               const float* __restrict__ Wk, const float* __restrict__ Wv,
               float* __restrict__ out) {
    // VT4: [kt=128][d=4][pos=16] bf16; rows d={x0,x1,x2,ones}; key m at pos pi(m)
    //      (pi = bit2<->bit3 swap). Serves PV-B (2x b128 broadcast reads). 16 KB
    // RED: [head4][wid8][slot][16] cross-wave partials (reused per pass)  16 KB
    __shared__ __align__(16) char VT4[128 * 128];
    __shared__ __align__(16) float RED[4][8][8][16];

    const int tid = threadIdx.x;
    const int blk = blockIdx.x;
    const int qb  = blk & 63;      // 32-query tile
    const int b   = blk >> 6;      // batch

    const float* xb = x + b * SEQ * 3;

    const int lane = tid & 63;
    const int wid  = tid >> 6;    // 8 waves: k-split 8-way, 256 keys per wave
    const int ql   = lane & 31;
    const int q    = qb * 32 + ql;
    const int kbase = wid * 256;

    // ---- A-fragments -> registers: lane's own key, 8 tiles per wave ----
    float ax0[8], ax1[8], ax2[8];
#pragma unroll
    for (int t = 0; t < 8; ++t) {
        const float* kp = xb + (kbase + t * 32 + ql) * 3;
        ax0[t] = kp[0]; ax1[t] = kp[1]; ax2[t] = kp[2];
    }

    // ---- staging: 4 keys per thread into VT4, pi-permuted positions ----
    {
        const float4* xg = (const float4*)xb;
        float xv[12];
        const float4 t0 = xg[tid * 3 + 0]; xv[0]=t0.x; xv[1]=t0.y; xv[2]=t0.z; xv[3]=t0.w;
        const float4 t1 = xg[tid * 3 + 1]; xv[4]=t1.x; xv[5]=t1.y; xv[6]=t1.z; xv[7]=t1.w;
        const float4 t2 = xg[tid * 3 + 2]; xv[8]=t2.x; xv[9]=t2.y; xv[10]=t2.z; xv[11]=t2.w;
        const int k0   = tid * 4;
        const int kt   = k0 >> 4;               // 16-key tile
        const int run  = k0 & 12;               // 4-key run within tile
        const int slotA = (run & 3) | ((run & 4) << 1) | ((run & 8) >> 1);  // pi(run)
        char* base = VT4 + kt * 128;
#pragma unroll
        for (int d = 0; d < 3; ++d) {
            uint2 wa;
            wa.x = pkb(xv[0 + d], xv[3 + d]);
            wa.y = pkb(xv[6 + d], xv[9 + d]);
            *(uint2*)(base + d * 32 + slotA * 2) = wa;
        }
        uint2 ones; ones.x = ones.y = 0x3F803F80u;
        *(uint2*)(base + 96 + (k0 & 15) * 2) = ones;
    }

    // pack A-frag registers: A0 full, A1 halves packed 2-tiles-per-reg
    u32 A0[8], A1h[4];
#pragma unroll
    for (int t = 0; t < 8; ++t) A0[t] = pkb(ax0[t], ax1[t]);
#pragma unroll
    for (int j = 0; j < 4; ++j) A1h[j] = pkb(ax2[2 * j], ax2[2 * j + 1]);

    // u-vectors for ALL EIGHT heads, PRE-SCALED by 2^7 (mantissa trick)
    const float* gq = xb + q * 3;
    const float xq0 = gq[0], xq1 = gq[1], xq2 = gq[2];
    const float cc = 0.5773502691896258f * 1.4426950408889634f * 128.0f;
    u32 BsW[8][2];
#pragma unroll
    for (int hh = 0; hh < 8; ++hh) {
        const float* wqp = Wq + hh * 9;
        const float* wkp = Wk + hh * 9;
        const float Q0 = xq0 * wqp[0] + xq1 * wqp[3] + xq2 * wqp[6];
        const float Q1 = xq0 * wqp[1] + xq1 * wqp[4] + xq2 * wqp[7];
        const float Q2 = xq0 * wqp[2] + xq1 * wqp[5] + xq2 * wqp[8];
        const float u0 = (Q0 * wkp[0] + Q1 * wkp[1] + Q2 * wkp[2]) * cc;
        const float u1 = (Q0 * wkp[3] + Q1 * wkp[4] + Q2 * wkp[5]) * cc;
        const float u2 = (Q0 * wkp[6] + Q1 * wkp[7] + Q2 * wkp[8]) * cc;
        BsW[hh][0] = (lane < 32) ? pkb(u0, u1) : 0u;
        BsW[hh][1] = (lane < 32) ? pkb(u2, 0.f) : 0u;
    }

    __syncthreads();

    // PV-B address: wave's 8 tiles start at kt = wid*16 (2048 B per wave)
    const char* vb = VT4 + wid * 2048 + (lane & 3) * 32 + (lane >> 5) * 16;

    f32x16_t bc;                      // mantissa-trick bias as MFMA C-operand
#pragma unroll
    for (int i = 0; i < 16; ++i) bc[i] = 8404864.0f;   // 2^23 + 127*2^7

    const int d31 = lane & 31;
    const int slot = ((lane >> 5) << 2) | d31;
    const int second = NB * NH * SEQ * 3;

    // ---- TWO PASSES over the same staged data: head-quad per pass ----
#pragma unroll
    for (int hq = 0; hq < 2; ++hq) {
        const int hbase = hq * 4;
        UBv Bs0, Bs1, Bs2, Bs3;
        Bs0.u[0] = BsW[hbase + 0][0]; Bs0.u[1] = BsW[hbase + 0][1]; Bs0.u[2] = 0u; Bs0.u[3] = 0u;
        Bs1.u[0] = BsW[hbase + 1][0]; Bs1.u[1] = BsW[hbase + 1][1]; Bs1.u[2] = 0u; Bs1.u[3] = 0u;
        Bs2.u[0] = BsW[hbase + 2][0]; Bs2.u[1] = BsW[hbase + 2][1]; Bs2.u[2] = 0u; Bs2.u[3] = 0u;
        Bs3.u[0] = BsW[hbase + 3][0]; Bs3.u[1] = BsW[hbase + 3][1]; Bs3.u[2] = 0u; Bs3.u[3] = 0u;

        f32x16_t pv0 = {}, pv1 = {}, pv2 = {}, pv3 = {};

#pragma unroll
        for (int t = 0; t < 8; ++t) {
            const uint4 bv0 = *(const uint4*)(vb + t * 256);
            const uint4 bv1 = *(const uint4*)(vb + t * 256 + 128);
            UBv B0; B0.u[0] = bv0.x; B0.u[1] = bv0.y; B0.u[2] = bv0.z; B0.u[3] = bv0.w;
            UBv B1; B1.u[0] = bv1.x; B1.u[1] = bv1.y; B1.u[2] = bv1.z; B1.u[3] = bv1.w;

            UBv A;
            A.u[0] = A0[t];
            A.u[1] = (t & 1) ? (A1h[t >> 1] >> 16) : (A1h[t >> 1] & 0xFFFFu);
            A.u[2] = 0u; A.u[3] = 0u;

            {
                const f32x16_t sc = __builtin_amdgcn_mfma_f32_32x32x16_bf16(A.v, Bs0.v, bc, 0, 0, 0);
                UBv PA;
                PA.u[0] = pks(sc[0],  sc[1]);  PA.u[1] = pks(sc[2],  sc[3]);
                PA.u[2] = pks(sc[4],  sc[5]);  PA.u[3] = pks(sc[6],  sc[7]);
                pv0 = __builtin_amdgcn_mfma_f32_32x32x16_bf16(PA.v, B0.v, pv0, 0, 0, 0);
                UBv PB;
                PB.u[0] = pks(sc[8],  sc[9]);  PB.u[1] = pks(sc[10], sc[11]);
                PB.u[2] = pks(sc[12], sc[13]); PB.u[3] = pks(sc[14], sc[15]);
                pv0 = __builtin_amdgcn_mfma_f32_32x32x16_bf16(PB.v, B1.v, pv0, 0, 0, 0);
            }
            {
                const f32x16_t sc = __builtin_amdgcn_mfma_f32_32x32x16_bf16(A.v, Bs1.v, bc, 0, 0, 0);
                UBv PA;
                PA.u[0] = pks(sc[0],  sc[1]);  PA.u[1] = pks(sc[2],  sc[3]);
                PA.u[2] = pks(sc[4],  sc[5]);  PA.u[3] = pks(sc[6],  sc[7]);
                pv1 = __builtin_amdgcn_mfma_f32_32x32x16_bf16(PA.v, B0.v, pv1, 0, 0, 0);
                UBv PB;
                PB.u[0] = pks(sc[8],  sc[9]);  PB.u[1] = pks(sc[10], sc[11]);
                PB.u[2] = pks(sc[12], sc[13]); PB.u[3] = pks(sc[14], sc[15]);
                pv1 = __builtin_amdgcn_mfma_f32_32x32x16_bf16(PB.v, B1.v, pv1, 0, 0, 0);
            }
            {
                const f32x16_t sc = __builtin_amdgcn_mfma_f32_32x32x16_bf16(A.v, Bs2.v, bc, 0, 0, 0);
                UBv PA;
                PA.u[0] = pks(sc[0],  sc[1]);  PA.u[1] = pks(sc[2],  sc[3]);
                PA.u[2] = pks(sc[4],  sc[5]);  PA.u[3] = pks(sc[6],  sc[7]);
                pv2 = __builtin_amdgcn_mfma_f32_32x32x16_bf16(PA.v, B0.v, pv2, 0, 0, 0);
                UBv PB;
                PB.u[0] = pks(sc[8],  sc[9]);  PB.u[1] = pks(sc[10], sc[11]);
                PB.u[2] = pks(sc[12], sc[13]); PB.u[3] = pks(sc[14], sc[15]);
                pv2 = __builtin_amdgcn_mfma_f32_32x32x16_bf16(PB.v, B1.v, pv2, 0, 0, 0);
            }
            {
                const f32x16_t sc = __builtin_amdgcn_mfma_f32_32x32x16_bf16(A.v, Bs3.v, bc, 0, 0, 0);
                UBv PA;
                PA.u[0] = pks(sc[0],  sc[1]);  PA.u[1] = pks(sc[2],  sc[3]);
                PA.u[2] = pks(sc[4],  sc[5]);  PA.u[3] = pks(sc[6],  sc[7]);
                pv3 = __builtin_amdgcn_mfma_f32_32x32x16_bf16(PA.v, B0.v, pv3, 0, 0, 0);
                UBv PB;
                PB.u[0] = pks(sc[8],  sc[9]);  PB.u[1] = pks(sc[10], sc[11]);
                PB.u[2] = pks(sc[12], sc[13]); PB.u[3] = pks(sc[14], sc[15]);
                pv3 = __builtin_amdgcn_mfma_f32_32x32x16_bf16(PB.v, B1.v, pv3, 0, 0, 0);
            }
        }

        // dump partials (RED reused across passes; sync'd below)
        if (d31 < 4) {
#pragma unroll
            for (int i = 0; i < 4; ++i) {
                float4 w;
                w.x = pv0[i*4+0]; w.y = pv0[i*4+1]; w.z = pv0[i*4+2]; w.w = pv0[i*4+3];
                *(float4*)&RED[0][wid][slot][i * 4] = w;
                w.x = pv1[i*4+0]; w.y = pv1[i*4+1]; w.z = pv1[i*4+2]; w.w = pv1[i*4+3];
                *(float4*)&RED[1][wid][slot][i * 4] = w;
                w.x = pv2[i*4+0]; w.y = pv2[i*4+1]; w.z = pv2[i*4+2]; w.w = pv2[i*4+3];
                *(float4*)&RED[2][wid][slot][i * 4] = w;
                w.x = pv3[i*4+0]; w.y = pv3[i*4+1]; w.z = pv3[i*4+2]; w.w = pv3[i*4+3];
                *(float4*)&RED[3][wid][slot][i * 4] = w;
            }
        }
        __syncthreads();

        // merge 8 k-splits + epilogue for this head-quad
        if (wid < 4 && lane < 32) {
            const int head = wid;
            const int hh   = hbase + head;
            const float* wvp = Wv + hh * 9;   // wave-uniform scalar loads
            const int qrow = lane;
            const int hh2 = (qrow >> 2) & 1;
            const int r   = (qrow & 3) | ((qrow >> 3) << 2);
            float acc[4];
#pragma unroll
            for (int d = 0; d < 4; ++d) {
                float s = 0.f;
#pragma unroll
                for (int w = 0; w < 8; ++w) s += RED[head][w][hh2 * 4 + d][r];
                acc[d] = s;
            }
            const float inv = 1.0f / fmaxf(acc[3], 1e-37f);
            const float r0 = acc[0] * inv, r1 = acc[1] * inv, r2 = acc[2] * inv;
            const float o0 = r0 * wvp[0] + r1 * wvp[3] + r2 * wvp[6];
            const float o1 = r0 * wvp[1] + r1 * wvp[4] + r2 * wvp[7];
            const float o2 = r0 * wvp[2] + r1 * wvp[5] + r2 * wvp[8];
            const int bhO = b * NH + hh;
            const int o   = bhO * (SEQ * 3) + (qb * 32 + qrow) * 3;
            out[o + 0] = o0; out[o + 1] = o1; out[o + 2] = o2;
            out[o + second + 0] = o0; out[o + second + 1] = o1; out[o + second + 2] = o2;
        }
        __syncthreads();   // protect RED reuse by next pass
    }
}

extern "C" void kernel_launch(void* const* d_in, const int* in_sizes, int n_in,
                              void* d_out, int out_size, void* d_ws, size_t ws_size,
                              hipStream_t stream) {
    const float* x  = (const float*)d_in[0];
    const float* Wq = (const float*)d_in[1];
    const float* Wk = (const float*)d_in[2];
    const float* Wv = (const float*)d_in[3];
    float* out = (float*)d_out;
    (void)in_sizes; (void)n_in; (void)d_ws; (void)ws_size; (void)out_size;

    const int grid = NB * (SEQ / 32);  // 256 blocks x 512 threads, 8 heads each
    attn_mfma<<<grid, 512, 0, stream>>>(x, Wq, Wk, Wv, out);
}